// Round 13
// baseline (710.546 us; speedup 1.0000x reference)
//
#include <hip/hip_runtime.h>
#include <stdint.h>
#include <stddef.h>

typedef _Float16 half8 __attribute__((ext_vector_type(8)));
typedef _Float16 half4v __attribute__((ext_vector_type(4)));
typedef float f32x4 __attribute__((ext_vector_type(4)));

__device__ __forceinline__ void gload_lds16(const void* g, void* l) {
  __builtin_amdgcn_global_load_lds((const __attribute__((address_space(1))) void*)g,
                                   (__attribute__((address_space(3))) void*)l, 16, 0, 0);
}

// ---------------- merged transpose+cast for all 5 feature tensors ----------------
struct TPack {
  const float* in[5];
  _Float16* out[5];
  int C[5], N[5];
  int cum[6];
};
__global__ __launch_bounds__(256) void k_transpose_all(TPack p) {
  __shared__ float tile[32][33];
  int t = blockIdx.x;
  int ti = 0;
#pragma unroll
  for (int i = 0; i < 5; ++i) if (t >= p.cum[i + 1]) ti = i + 1;
  int lt = t - p.cum[ti];
  int C = p.C[ti], N = p.N[ti];
  const float* in = p.in[ti];
  _Float16* out = p.out[ti];
  int tiles_n = (N + 31) / 32;
  int perb = (C / 32) * tiles_n;
  int b = lt / perb;
  int rem = lt - b * perb;
  int c0 = (rem / tiles_n) * 32;
  int n0 = (rem % tiles_n) * 32;
  int tx = threadIdx.x, ty = threadIdx.y;
#pragma unroll
  for (int j = 0; j < 32; j += 8) {
    int c = c0 + ty + j, n = n0 + tx;
    if (c < C && n < N) tile[ty + j][tx] = in[((size_t)b * C + c) * N + n];
  }
  __syncthreads();
#pragma unroll
  for (int j = 0; j < 32; j += 8) {
    int n = n0 + ty + j, c = c0 + tx;
    if (n < N && c < C) out[((size_t)b * N + n) * C + c] = (_Float16)tile[tx][ty + j];
  }
}

// ---------------- weight cast with zero row/K padding (single tensor) ----------------
__global__ __launch_bounds__(256) void k_cast_pad_w(const float* __restrict__ W,
                                                    _Float16* __restrict__ Wh,
                                                    int O, int K, int Opad, int Kpad) {
  size_t i = ((size_t)blockIdx.x * 256 + threadIdx.x) * 4;
  if (i >= (size_t)Opad * Kpad) return;
  int r = (int)(i / Kpad), k = (int)(i % Kpad);
  half4v v;
#pragma unroll
  for (int j = 0; j < 4; ++j) {
    float f = (r < O && (k + j) < K) ? W[(size_t)r * K + k + j] : 0.f;
    v[j] = (_Float16)f;
  }
  *(half4v*)(Wh + i) = v;
}

// ---------------- merged weight cast: all 5 weight tensors in one dispatch -----------
struct WPack {
  const float* in[5];
  _Float16* out[5];
  int O[5], K[5], Opad[5], Kpad[5];
  int cum[6];   // cumulative block counts (256 thr x 4 elem per block)
};
__global__ __launch_bounds__(256) void k_cast_all_w(WPack p) {
  int t = blockIdx.x;
  int ti = 0;
#pragma unroll
  for (int i = 0; i < 5; ++i) if (t >= p.cum[i + 1]) ti = i + 1;
  int lb = t - p.cum[ti];
  int O = p.O[ti], K = p.K[ti], Opad = p.Opad[ti], Kpad = p.Kpad[ti];
  const float* W = p.in[ti];
  _Float16* Wh = p.out[ti];
  size_t i = ((size_t)lb * 256 + threadIdx.x) * 4;
  if (i >= (size_t)Opad * Kpad) return;
  int r = (int)(i / Kpad), k = (int)(i % Kpad);
  half4v v;
#pragma unroll
  for (int j = 0; j < 4; ++j) {
    float f = (r < O && (k + j) < K) ? W[(size_t)r * K + k + j] : 0.f;
    v[j] = (_Float16)f;
  }
  *(half4v*)(Wh + i) = v;
}

// ---------------- merged 3-NN, 4 threads per query (source-split + shfl merge) --------
struct KPack {
  const float* q[4]; const float* p[4];
  int N1[4], S[4];
  int cum[5];
  int obase[4];
};
#define KNN_INS(dd, ii) { float _d = (dd); int _i = (ii); \
  if (_d < d0)      { d2 = d1; i2 = i1; d1 = d0; i1 = i0; d0 = _d; i0 = _i; } \
  else if (_d < d1) { d2 = d1; i2 = i1; d1 = _d; i1 = _i; } \
  else if (_d < d2) { d2 = _d; i2 = _i; } }
__global__ __launch_bounds__(256) void k_knn_all(KPack kp, int4* __restrict__ idxo,
                                                 float4* __restrict__ wo) {
  __shared__ float sp[512 * 3];
  __shared__ float spp[512];
  int t = blockIdx.x;
  int st = 0;
#pragma unroll
  for (int i = 0; i < 4; ++i) if (t >= kp.cum[i + 1]) st = i + 1;
  int lb = t - kp.cum[st];
  int N1 = kp.N1[st], S = kp.S[st];
  int nb = (N1 * 4 + 255) / 256;
  int b = lb / nb;
  int xb = lb - b * nb;
  const float* p = kp.p[st];
  const float* q = kp.q[st];
  for (int i = threadIdx.x; i < S * 3; i += 256) sp[i] = p[(size_t)b * S * 3 + i];
  __syncthreads();
  for (int s = threadIdx.x; s < S; s += 256)
    spp[s] = sp[s * 3] * sp[s * 3] + sp[s * 3 + 1] * sp[s * 3 + 1] + sp[s * 3 + 2] * sp[s * 3 + 2];
  __syncthreads();
  int tt = xb * 256 + threadIdx.x;
  int n = tt >> 2, sub = tt & 3;
  if (n >= N1) return;
  const float* qp = q + ((size_t)b * N1 + n) * 3;
  float qx = qp[0], qy = qp[1], qz = qp[2];
  float qq = qx * qx + qy * qy + qz * qz;
  float d0 = 1e30f, d1 = 1e30f, d2 = 1e30f;
  int i0 = 0, i1 = 0, i2 = 0;
  int Sq = S >> 2;
  int s0 = sub * Sq;
  for (int i = 0; i < Sq; ++i) {
    int s = s0 + i;
    float d = qq + spp[s] - 2.f * (qx * sp[s * 3] + qy * sp[s * 3 + 1] + qz * sp[s * 3 + 2]);
    KNN_INS(d, s);
  }
#pragma unroll
  for (int m = 1; m <= 2; m <<= 1) {
    float rd0 = __shfl_xor(d0, m, 64), rd1 = __shfl_xor(d1, m, 64), rd2 = __shfl_xor(d2, m, 64);
    int   ri0 = __shfl_xor(i0, m, 64), ri1 = __shfl_xor(i1, m, 64), ri2 = __shfl_xor(i2, m, 64);
    KNN_INS(rd0, ri0); KNN_INS(rd1, ri1); KNN_INS(rd2, ri2);
  }
  if (sub == 0) {
    float w0 = 1.f / (d0 + 1e-8f), w1 = 1.f / (d1 + 1e-8f), w2 = 1.f / (d2 + 1e-8f);
    float wsum = w0 + w1 + w2;
    int gi = kp.obase[st] + b * N1 + n;
    idxo[gi] = make_int4(b * S + i0, b * S + i1, b * S + i2, 0);
    wo[gi] = make_float4(w0 / wsum, w1 / wsum, w2 / wsum, 0.f);
  }
}

__global__ __launch_bounds__(256) void k_bn_finalize(const float* __restrict__ sum,
                                                     const float* __restrict__ sumsq,
                                                     const float* __restrict__ g, const float* __restrict__ b,
                                                     float* __restrict__ scale, float* __restrict__ shiftv,
                                                     int O, int Opad, float invM) {
  int c = blockIdx.x * 256 + threadIdx.x;
  if (c >= Opad) return;
  if (c < O) {
    float mean = sum[c] * invM;
    float var = sumsq[c] * invM - mean * mean;
    float sc = g[c] * rsqrtf(var + 1e-5f);
    scale[c] = sc;
    shiftv[c] = b[c] - mean * sc;
  } else {
    scale[c] = 0.f;
    shiftv[c] = 0.f;
  }
}

// ---------------- reduce per-block private stats -> sum/sumsq (stage-3 full path) -----
// pstats layout: [(o*256+m)*256] : [0..127]=sum partials, [128..255]=sumsq partials
__global__ __launch_bounds__(256) void k_stat_reduce(const float* __restrict__ ps,
                                                     float* __restrict__ sum,
                                                     float* __restrict__ sumsq, int nm) {
  int o = blockIdx.x;
  int t = threadIdx.x;
  float acc = 0.f;
  for (int m = 0; m < nm; ++m)
    acc += ps[((size_t)(o * 256 + m)) * 256 + t];
  if (t < 128) sum[o * 128 + t] = acc;
  else         sumsq[o * 128 + (t - 128)] = acc;
}

// ======== XOR-swizzled LDS GEMMs (conflict-free, verified R6-R12) ========

// ---------------- GEMM, optional fused BN+ReLU on A, f16 out ----------------
__global__ __launch_bounds__(256) void k_gemm_anorm(const _Float16* __restrict__ A,
                                                    const float* __restrict__ scale,
                                                    const float* __restrict__ shift,
                                                    int apply_nr,
                                                    const _Float16* __restrict__ W,
                                                    _Float16* __restrict__ Cout,
                                                    int K, int lda, int ldb, int ldc) {
  __shared__ __align__(16) _Float16 lA[128 * 64];
  __shared__ __align__(16) _Float16 lB[128 * 64];
  int tid = threadIdx.x;
  int m0 = blockIdx.x * 128;
  int o0 = blockIdx.y * 128;
  int lane = tid & 63, wv = tid >> 6;
  int wm = (wv & 1) * 64, wo = (wv >> 1) * 64;
  int lr = lane & 15, lq = lane >> 4;
  int trow = tid >> 3;
  int tsegl = (((tid & 7) ^ (trow & 7))) * 8;
  int sw = lr & 7;

  f32x4 acc[4][4];
#pragma unroll
  for (int mi = 0; mi < 4; ++mi)
#pragma unroll
    for (int oi = 0; oi < 4; ++oi)
      acc[mi][oi] = (f32x4){0.f, 0.f, 0.f, 0.f};

  const _Float16* gA = A + (size_t)(m0 + trow) * lda + tsegl;
  const _Float16* gB = W + (size_t)(o0 + trow) * ldb + tsegl;

  for (int k0 = 0; k0 < K; k0 += 64) {
#pragma unroll
    for (int i = 0; i < 4; ++i)
      gload_lds16(gB + (size_t)(32 * i) * ldb + k0, lB + ((size_t)i * 256 + tid) * 8);
    if (apply_nr) {
      float sc[8], sh[8];
#pragma unroll
      for (int j = 0; j < 8; ++j) { sc[j] = scale[k0 + tsegl + j]; sh[j] = shift[k0 + tsegl + j]; }
#pragma unroll
      for (int i = 0; i < 4; ++i) {
        half8 v = *(const half8*)(gA + (size_t)(32 * i) * lda + k0);
        half8 o;
#pragma unroll
        for (int j = 0; j < 8; ++j)
          o[j] = (_Float16)fmaxf((float)v[j] * sc[j] + sh[j], 0.f);
        *(half8*)&lA[((size_t)i * 256 + tid) * 8] = o;
      }
    } else {
#pragma unroll
      for (int i = 0; i < 4; ++i)
        gload_lds16(gA + (size_t)(32 * i) * lda + k0, lA + ((size_t)i * 256 + tid) * 8);
    }
    __syncthreads();
#pragma unroll
    for (int ks = 0; ks < 64; ks += 32) {
      half8 af[4], bf[4];
#pragma unroll
      for (int mi = 0; mi < 4; ++mi)
        af[mi] = *(const half8*)&lA[(wm + mi * 16 + lr) * 64 + ((((ks >> 3) + lq) ^ sw)) * 8];
#pragma unroll
      for (int oi = 0; oi < 4; ++oi)
        bf[oi] = *(const half8*)&lB[(wo + oi * 16 + lr) * 64 + ((((ks >> 3) + lq) ^ sw)) * 8];
#pragma unroll
      for (int mi = 0; mi < 4; ++mi)
#pragma unroll
        for (int oi = 0; oi < 4; ++oi)
          acc[mi][oi] = __builtin_amdgcn_mfma_f32_16x16x32_f16(af[mi], bf[oi], acc[mi][oi], 0, 0, 0);
    }
    __syncthreads();
  }

#pragma unroll
  for (int mi = 0; mi < 4; ++mi)
#pragma unroll
    for (int oi = 0; oi < 4; ++oi) {
      int col = o0 + wo + oi * 16 + lr;
      int rowb = m0 + wm + mi * 16 + lq * 4;
#pragma unroll
      for (int r = 0; r < 4; ++r)
        Cout[(size_t)(rowb + r) * ldc + col] = (_Float16)acc[mi][oi][r];
    }
}

// ---- FUSED 128x128: Y = skip.Wskip^T + interp(Z); vectorized epilogue; opt XCD swizzle;
//      stats via global atomics (pstats==null) or per-block private scratch ----
__global__ __launch_bounds__(256) void k_gemm_yis(const _Float16* __restrict__ A,
                                                  const _Float16* __restrict__ W,
                                                  const _Float16* __restrict__ Z,
                                                  const int4* __restrict__ idxb,
                                                  const float4* __restrict__ wb,
                                                  _Float16* __restrict__ Y,
                                                  float* __restrict__ sum,
                                                  float* __restrict__ sumsq,
                                                  float* __restrict__ pstats,
                                                  int K, int lda, int ldb, int ldy,
                                                  int ldz, int zcol0, int swz) {
  __shared__ __align__(16) _Float16 lsm[2 * 128 * 64];
  __shared__ int4 sIdx[128];
  __shared__ float4 sWt[128];
  __shared__ float sStat[256];
  _Float16* lA = lsm;
  _Float16* lB = lsm + 128 * 64;
  int tid = threadIdx.x;
  int m0, o0;
  if (swz) {
    // XCD-aware (R10-verified: FETCH 120->57MB)
    int bid = blockIdx.y * gridDim.x + blockIdx.x;
    int o = (bid & 7) + ((bid >> 11) << 3);
    int m = (bid >> 3) & 255;
    m0 = m * 128; o0 = o * 128;
  } else {
    m0 = blockIdx.x * 128; o0 = blockIdx.y * 128;
  }
  if (tid < 128) {
    sIdx[tid] = idxb[m0 + tid];
    sWt[tid] = wb[m0 + tid];
  }
  sStat[tid] = 0.f;
  int lane = tid & 63, wv = tid >> 6;
  int wm = (wv & 1) * 64, wo = (wv >> 1) * 64;
  int lr = lane & 15, lq = lane >> 4;
  int trow = tid >> 3;
  int tsegl = (((tid & 7) ^ (trow & 7))) * 8;
  int sw = lr & 7;

  f32x4 acc[4][4];
#pragma unroll
  for (int mi = 0; mi < 4; ++mi)
#pragma unroll
    for (int oi = 0; oi < 4; ++oi)
      acc[mi][oi] = (f32x4){0.f, 0.f, 0.f, 0.f};

  const _Float16* gA = A + (size_t)(m0 + trow) * lda + tsegl;
  const _Float16* gB = W + (size_t)(o0 + trow) * ldb + tsegl;

  for (int k0 = 0; k0 < K; k0 += 64) {
#pragma unroll
    for (int i = 0; i < 4; ++i) {
      gload_lds16(gA + (size_t)(32 * i) * lda + k0, lA + ((size_t)i * 256 + tid) * 8);
      gload_lds16(gB + (size_t)(32 * i) * ldb + k0, lB + ((size_t)i * 256 + tid) * 8);
    }
    __syncthreads();
#pragma unroll
    for (int ks = 0; ks < 64; ks += 32) {
      half8 af[4], bf[4];
#pragma unroll
      for (int mi = 0; mi < 4; ++mi)
        af[mi] = *(const half8*)&lA[(wm + mi * 16 + lr) * 64 + ((((ks >> 3) + lq) ^ sw)) * 8];
#pragma unroll
      for (int oi = 0; oi < 4; ++oi)
        bf[oi] = *(const half8*)&lB[(wo + oi * 16 + lr) * 64 + ((((ks >> 3) + lq) ^ sw)) * 8];
#pragma unroll
      for (int mi = 0; mi < 4; ++mi)
#pragma unroll
        for (int oi = 0; oi < 4; ++oi)
          acc[mi][oi] = __builtin_amdgcn_mfma_f32_16x16x32_f16(af[mi], bf[oi], acc[mi][oi], 0, 0, 0);
    }
    __syncthreads();
  }

#pragma unroll
  for (int mi = 0; mi < 4; ++mi)
#pragma unroll
    for (int oi = 0; oi < 4; ++oi)
#pragma unroll
      for (int r = 0; r < 4; ++r)
        lsm[(wm + mi * 16 + lq * 4 + r) * 128 + (wo + oi * 16 + lr)] = (_Float16)acc[mi][oi][r];
  __syncthreads();

  int tcol = (tid & 15) * 8;
  int rbase = tid >> 4;
  float s8[8], q8[8];
#pragma unroll
  for (int j = 0; j < 8; ++j) { s8[j] = 0.f; q8[j] = 0.f; }
#pragma unroll
  for (int i = 0; i < 8; ++i) {
    int row = rbase + i * 16;
    int4 id = sIdx[row];
    float4 w = sWt[row];
    half8 y = *(half8*)&lsm[row * 128 + tcol];
    int zc = zcol0 + o0 + tcol;
    half8 a  = *(const half8*)&Z[(size_t)id.x * ldz + zc];
    half8 b2 = *(const half8*)&Z[(size_t)id.y * ldz + zc];
    half8 c2 = *(const half8*)&Z[(size_t)id.z * ldz + zc];
    half8 o;
#pragma unroll
    for (int j = 0; j < 8; ++j) {
      float v = (float)y[j] + w.x * (float)a[j] + w.y * (float)b2[j] + w.z * (float)c2[j];
      o[j] = (_Float16)v;
      s8[j] += v; q8[j] += v * v;
    }
    *(half8*)&Y[(size_t)(m0 + row) * ldy + o0 + tcol] = o;
  }
#pragma unroll
  for (int j = 0; j < 8; ++j) {
    atomicAdd(&sStat[tcol + j], s8[j]);
    atomicAdd(&sStat[128 + tcol + j], q8[j]);
  }
  __syncthreads();
  if (tid < 128) {
    if (pstats) {
      // private per-block slot: no global atomic contention
      float* dst = pstats + ((size_t)((o0 >> 7) * 256 + (m0 >> 7))) * 256;
      dst[tid] = sStat[tid];
      dst[128 + tid] = sStat[128 + tid];
    } else {
      atomicAdd(&sum[o0 + tid], sStat[tid]);
      atomicAdd(&sumsq[o0 + tid], sStat[128 + tid]);
    }
  }
}

// ---- decoder GEMM: folded BN-finalize + normrelu on A, f32 out/acc into D,
//      optional fused D-stats; swz pairs (m,o=0)/(m,o=1) on one XCD for Y3 L2 reuse ----
__global__ __launch_bounds__(256) void k_gemm_dec_acc(const _Float16* __restrict__ A,
                                                      const float* __restrict__ sumc,
                                                      const float* __restrict__ sumsqc,
                                                      const float* __restrict__ g,
                                                      const float* __restrict__ b,
                                                      float invM, int c0, int Oglob,
                                                      const _Float16* __restrict__ W,
                                                      float* __restrict__ D,
                                                      int K, int lda, int ldb, int ldc,
                                                      int accum, int do_stats, int swz,
                                                      float* __restrict__ dsum,
                                                      float* __restrict__ dsumsq) {
  __shared__ __align__(16) _Float16 lA[128 * 64];
  __shared__ __align__(16) _Float16 lB[128 * 64];
  __shared__ float sScale[2048];
  __shared__ float sShift[2048];
  __shared__ float sStat[256];
  int tid = threadIdx.x;
  int m0, o0;
  if (swz) {
    int bid = blockIdx.y * gridDim.x + blockIdx.x;
    int mlow = bid & 7, oo = (bid >> 3) & 1, mhigh = bid >> 4;
    m0 = (mhigh * 8 + mlow) * 128;
    o0 = oo * 128;
  } else {
    m0 = blockIdx.x * 128; o0 = blockIdx.y * 128;
  }
  for (int c = tid; c < K; c += 256) {
    int gc = c0 + c;
    float sc = 0.f, sh = 0.f;
    if (gc < Oglob) {
      float mean = sumc[c] * invM;
      float var = sumsqc[c] * invM - mean * mean;
      sc = g[gc] * rsqrtf(var + 1e-5f);
      sh = b[gc] - mean * sc;
    }
    sScale[c] = sc; sShift[c] = sh;
  }
  sStat[tid] = 0.f;
  __syncthreads();

  int lane = tid & 63, wv = tid >> 6;
  int wm = (wv & 1) * 64, wo = (wv >> 1) * 64;
  int lr = lane & 15, lq = lane >> 4;
  int trow = tid >> 3;
  int tsegl = (((tid & 7) ^ (trow & 7))) * 8;
  int sw = lr & 7;

  f32x4 acc[4][4];
#pragma unroll
  for (int mi = 0; mi < 4; ++mi)
#pragma unroll
    for (int oi = 0; oi < 4; ++oi)
      acc[mi][oi] = (f32x4){0.f, 0.f, 0.f, 0.f};

  const _Float16* gA = A + (size_t)(m0 + trow) * lda + tsegl;
  const _Float16* gB = W + (size_t)(o0 + trow) * ldb + tsegl;

  for (int k0 = 0; k0 < K; k0 += 64) {
#pragma unroll
    for (int i = 0; i < 4; ++i)
      gload_lds16(gB + (size_t)(32 * i) * ldb + k0, lB + ((size_t)i * 256 + tid) * 8);
    float sc[8], sh[8];
#pragma unroll
    for (int j = 0; j < 8; ++j) { sc[j] = sScale[k0 + tsegl + j]; sh[j] = sShift[k0 + tsegl + j]; }
#pragma unroll
    for (int i = 0; i < 4; ++i) {
      half8 v = *(const half8*)(gA + (size_t)(32 * i) * lda + k0);
      half8 o;
#pragma unroll
      for (int j = 0; j < 8; ++j)
        o[j] = (_Float16)fmaxf((float)v[j] * sc[j] + sh[j], 0.f);
      *(half8*)&lA[((size_t)i * 256 + tid) * 8] = o;
    }
    __syncthreads();
#pragma unroll
    for (int ks = 0; ks < 64; ks += 32) {
      half8 af[4], bf[4];
#pragma unroll
      for (int mi = 0; mi < 4; ++mi)
        af[mi] = *(const half8*)&lA[(wm + mi * 16 + lr) * 64 + ((((ks >> 3) + lq) ^ sw)) * 8];
#pragma unroll
      for (int oi = 0; oi < 4; ++oi)
        bf[oi] = *(const half8*)&lB[(wo + oi * 16 + lr) * 64 + ((((ks >> 3) + lq) ^ sw)) * 8];
#pragma unroll
      for (int mi = 0; mi < 4; ++mi)
#pragma unroll
        for (int oi = 0; oi < 4; ++oi)
          acc[mi][oi] = __builtin_amdgcn_mfma_f32_16x16x32_f16(af[mi], bf[oi], acc[mi][oi], 0, 0, 0);
    }
    __syncthreads();
  }

  float ps[4], pq[4];
#pragma unroll
  for (int oi = 0; oi < 4; ++oi) { ps[oi] = 0.f; pq[oi] = 0.f; }
#pragma unroll
  for (int mi = 0; mi < 4; ++mi)
#pragma unroll
    for (int oi = 0; oi < 4; ++oi) {
      int col = o0 + wo + oi * 16 + lr;
      int rowb = m0 + wm + mi * 16 + lq * 4;
#pragma unroll
      for (int r = 0; r < 4; ++r) {
        size_t idx = (size_t)(rowb + r) * ldc + col;
        float v = acc[mi][oi][r];
        if (accum) v += D[idx];
        D[idx] = v;
        if (do_stats) { ps[oi] += v; pq[oi] += v * v; }
      }
    }
  if (do_stats) {
#pragma unroll
    for (int oi = 0; oi < 4; ++oi) {
      int tc = wo + oi * 16 + lr;
      atomicAdd(&sStat[tc], ps[oi]);
      atomicAdd(&sStat[128 + tc], pq[oi]);
    }
    __syncthreads();
    if (tid < 128) {
      atomicAdd(&dsum[o0 + tid], sStat[tid]);
      atomicAdd(&dsumsq[o0 + tid], sStat[128 + tid]);
    }
  }
}

// ---------------- final dot; BN finalize hoisted into LDS once per block ----------------
__global__ __launch_bounds__(256) void k_final_dot2(const float* __restrict__ H,
                                                    const float* __restrict__ w,
                                                    const float* __restrict__ dsum,
                                                    const float* __restrict__ dsumsq,
                                                    const float* __restrict__ g,
                                                    const float* __restrict__ b,
                                                    float invM,
                                                    float* __restrict__ out, int Mtot) {
  __shared__ float sSc[256], sSh[256];
  int tid = threadIdx.x;
  {
    int c = tid;
    float mean = dsum[c] * invM;
    float var = dsumsq[c] * invM - mean * mean;
    float sc = g[c] * rsqrtf(var + 1e-5f);
    sSc[c] = sc;
    sSh[c] = b[c] - mean * sc;
  }
  __syncthreads();
  int lane = tid & 63, wv = tid >> 6;
  int r = blockIdx.x * 4 + wv;
  if (r >= Mtot) return;
  const float* h = H + (size_t)r * 256;
  float s = 0.f;
  for (int c = lane; c < 256; c += 64)
    s += fmaxf(h[c] * sSc[c] + sSh[c], 0.f) * w[c];
#pragma unroll
  for (int o = 32; o > 0; o >>= 1) s += __shfl_down(s, o, 64);
  if (lane == 0) out[r] = s;
}

extern "C" void kernel_launch(void* const* d_in, const int* in_sizes, int n_in,
                              void* d_out, int out_size, void* d_ws, size_t ws_size,
                              hipStream_t stream) {
  (void)in_sizes; (void)n_in; (void)out_size;
  const int B = 16;
  const float* xyzs[5]; const float* xs[5];
  for (int i = 0; i < 5; ++i) { xyzs[i] = (const float*)d_in[2 * i]; xs[i] = (const float*)d_in[2 * i + 1]; }
  const float* wlin[4] = {(const float*)d_in[10], (const float*)d_in[13], (const float*)d_in[16], (const float*)d_in[19]};
  const float* glin[4] = {(const float*)d_in[11], (const float*)d_in[14], (const float*)d_in[17], (const float*)d_in[20]};
  const float* blin[4] = {(const float*)d_in[12], (const float*)d_in[15], (const float*)d_in[18], (const float*)d_in[21]};
  const float* wdec0 = (const float*)d_in[22];
  const float* gdec  = (const float*)d_in[23];
  const float* bdec  = (const float*)d_in[24];
  const float* wdec1 = (const float*)d_in[25];
  float* outp = (float*)d_out;

  const int ch[5] = {64, 128, 256, 512, 1024};
  const int np[5] = {2048, 512, 128, 32, 8};

  char* base = (char*)d_ws;
  size_t off = 0;
  auto alloc = [&](size_t bytes) -> char* {
    char* p = base + off;
    off += (bytes + 255) & ~(size_t)255;
    return p;
  };

  // ---- base allocations (weight-independent) ----
  _Float16* tT[5];
  for (int i = 0; i < 5; ++i) tT[i] = (_Float16*)alloc((size_t)B * np[i] * ch[i] * 2);
  int4* idxAll = (int4*)alloc(43520 * sizeof(int4));
  float4* wbAll = (float4*)alloc(43520 * sizeof(float4));
  float* statsPool = (float*)alloc(8 * 2 * 2048 * sizeof(float));
  float* scaleA = (float*)alloc(2048 * sizeof(float));
  float* shiftA = (float*)alloc(2048 * sizeof(float));
  _Float16* Zreg = (_Float16*)alloc((size_t)8192 * 2048 * 2);
  float* D = (float*)alloc((size_t)32768 * 256 * 4);   // also reused as yis3 stat scratch
  size_t off_base = off;

  const int WO[5]   = {1536, 1792, 1920, 1984, 256};
  const int WOp[5]  = {1536, 1792, 1920, 2048, 256};
  const int WK[5]   = {1536, 1792, 1920, 1984, 1984};
  const int WKp[5]  = {1536, 1792, 1920, 1984, 2048};
  size_t wall_bytes = 0;
  for (int i = 0; i < 5; ++i) wall_bytes += (((size_t)WOp[i] * WKp[i] * 2) + 255) & ~(size_t)255;
  size_t wshared_bytes = ((((size_t)2048 * 1984 * 2) + 255) & ~(size_t)255) +
                         ((((size_t)256 * 2048 * 2) + 255) & ~(size_t)255);
  size_t ybytes_chunk = 40370176;
  size_t ybytes_full = (size_t)32768 * 2048 * 2;

  int gate_w    = (ws_size >= off_base + wall_bytes + ybytes_full + 512);
  int use_full  = gate_w || (ws_size >= off_base + wshared_bytes + ybytes_full + 512);

  _Float16* Wst[4];  // per-stage weight buffers (gate_w: distinct; else shared Wbuf)
  _Float16* Wdec;
  _Float16* Wbuf = nullptr;
  if (gate_w) {
    for (int i = 0; i < 4; ++i) Wst[i] = (_Float16*)alloc((size_t)WOp[i] * WKp[i] * 2);
    Wdec = (_Float16*)alloc((size_t)256 * 2048 * 2);
  } else {
    Wbuf = (_Float16*)alloc((size_t)2048 * 1984 * 2);
    for (int i = 0; i < 4; ++i) Wst[i] = Wbuf;
    Wdec = (_Float16*)alloc((size_t)256 * 2048 * 2);
  }
  char* Yreg = alloc(use_full ? ybytes_full : ybytes_chunk);
  _Float16* Y0 = (_Float16*)Yreg;
  _Float16* Y1 = (_Float16*)(Yreg + (size_t)512 * 1536 * 2);
  _Float16* Y2 = (_Float16*)(Yreg + (size_t)(512 * 1536 + 2048 * 1792) * 2);
  _Float16* Ychunk = (_Float16*)Yreg;
  _Float16* Y3full = (_Float16*)Yreg;
  if (off > ws_size) return;

  hipMemsetAsync(statsPool, 0, 8 * 2 * 2048 * sizeof(float), stream);

  // merged transpose
  {
    TPack p;
    int cum = 0;
    for (int i = 0; i < 5; ++i) {
      p.in[i] = xs[i]; p.out[i] = tT[i]; p.C[i] = ch[i]; p.N[i] = np[i];
      p.cum[i] = cum;
      cum += (ch[i] / 32) * ((np[i] + 31) / 32) * B;
    }
    p.cum[5] = cum;
    k_transpose_all<<<cum, dim3(32, 8), 0, stream>>>(p);
  }

  // weight casts: one merged dispatch when room, else per-use below
  const float* wsrc[5] = {wlin[0], wlin[1], wlin[2], wlin[3], wdec0};
  if (gate_w) {
    WPack p;
    int cum = 0;
    for (int i = 0; i < 5; ++i) {
      p.in[i] = wsrc[i];
      p.out[i] = (i < 4) ? Wst[i] : Wdec;
      p.O[i] = WO[i]; p.K[i] = WK[i]; p.Opad[i] = WOp[i]; p.Kpad[i] = WKp[i];
      p.cum[i] = cum;
      cum += (int)(((size_t)WOp[i] * WKp[i] / 4 + 255) / 256);
    }
    p.cum[5] = cum;
    k_cast_all_w<<<cum, 256, 0, stream>>>(p);
  } else {
    size_t tot4 = (size_t)256 * 2048 / 4;
    k_cast_pad_w<<<(unsigned)((tot4 + 255) / 256), 256, 0, stream>>>(wdec0, Wdec, 256, 1984, 256, 2048);
  }

  const int N1s[4] = {32, 128, 512, 2048};
  const int Ss[4]  = {8, 32, 128, 512};
  const int C1s[4] = {512, 256, 128, 64};
  const int C2s[4] = {1024, 1536, 1792, 1920};
  const int Os[4]  = {1536, 1792, 1920, 1984};
  const int obase[4] = {0, 512, 2560, 10752};
  _Float16* Ys[3] = {Y0, Y1, Y2};

  // merged kNN (4 threads per query)
  {
    KPack kp;
    int cum = 0;
    for (int st = 0; st < 4; ++st) {
      kp.q[st] = xyzs[3 - st]; kp.p[st] = xyzs[4 - st];
      kp.N1[st] = N1s[st]; kp.S[st] = Ss[st];
      kp.cum[st] = cum;
      cum += ((N1s[st] * 4 + 255) / 256) * B;
      kp.obase[st] = obase[st];
    }
    kp.cum[4] = cum;
    k_knn_all<<<cum, 256, 0, stream>>>(kp, idxAll, wbAll);
  }

  // ---- stages 0..2 ----
  for (int st = 0; st < 3; ++st) {
    int N1 = N1s[st], C1 = C1s[st], C2 = C2s[st], O = Os[st];
    int Ktot = C1 + C2;
    int M = B * N1, Msrc = B * Ss[st];
    const _Float16* H = (st == 0) ? tT[4] : Ys[st - 1];
    _Float16* Y = Ys[st];
    float* sum = statsPool + st * 2 * 2048;
    float* sumsq = sum + 2048;

    if (!gate_w) {
      size_t wt = (size_t)O * Ktot / 4;
      k_cast_pad_w<<<(unsigned)((wt + 255) / 256), 256, 0, stream>>>(wlin[st], Wbuf, O, Ktot, O, Ktot);
    }
    k_gemm_anorm<<<dim3(Msrc / 128, O / 128), 256, 0, stream>>>(H, scaleA, shiftA, st != 0,
                                                                Wst[st] + C1, Zreg, C2, C2, Ktot, O);
    k_gemm_yis<<<dim3(M / 128, O / 128), 256, 0, stream>>>(tT[3 - st], Wst[st], Zreg,
                                                           idxAll + obase[st], wbAll + obase[st],
                                                           Y, sum, sumsq, nullptr,
                                                           C1, C1, Ktot, O, O, 0, 0);
    k_bn_finalize<<<(O + 255) / 256, 256, 0, stream>>>(sum, sumsq, glin[st], blin[st], scaleA, shiftA, O, O, 1.f / M);
  }

  // ---- stage 3 ----
  {
    int C1 = 64, C2 = 1920, O = 1984, M = 32768, Msrc = 8192;
    int Ktot = 1984;
    if (!gate_w) {
      size_t wt = (size_t)2048 * Ktot / 4;
      k_cast_pad_w<<<(unsigned)((wt + 255) / 256), 256, 0, stream>>>(wlin[3], Wbuf, O, Ktot, 2048, Ktot);
    }

    // Z3 (8192 x 2048) = normrelu(Y2) . Wint^T (fused anorm)
    k_gemm_anorm<<<dim3(Msrc / 128, 16), 256, 0, stream>>>(Y2, scaleA, shiftA, 1,
                                                           Wst[3] + C1, Zreg, C2, C2, Ktot, 2048);

    float* dsum = statsPool + 7 * 2 * 2048;
    float* dsumsq = dsum + 2048;
    if (use_full) {
      float* sum = statsPool + 3 * 2 * 2048;
      float* sumsq = sum + 2048;
      // Y3 (32768 x 2048), XCD-swizzled, per-block private stats into D-scratch
      k_gemm_yis<<<dim3(256, 16), 256, 0, stream>>>(tT[0], Wst[3], Zreg,
                                                    idxAll + obase[3], wbAll + obase[3],
                                                    Y3full, sum, sumsq, D,
                                                    C1, C1, Ktot, 2048, 2048, 0, 1);
      k_stat_reduce<<<16, 256, 0, stream>>>(D, sum, sumsq, 256);
      // D = normrelu(Y3).Wdec^T, K=2048, pair-swizzled, fused D-stats
      k_gemm_dec_acc<<<dim3(256, 2), 256, 0, stream>>>(Y3full, sum, sumsq,
                                                       glin[3], blin[3], 1.f / M, 0, O,
                                                       Wdec, D, 2048, 2048, 2048, 256,
                                                       0, 1, 1, dsum, dsumsq);
    } else {
      for (int c0 = 0; c0 < 2048; c0 += 512) {
        float* sum = statsPool + (3 + c0 / 512) * 2 * 2048;
        float* sumsq = sum + 2048;
        k_gemm_yis<<<dim3(M / 128, 4), 256, 0, stream>>>(tT[0], Wst[3] + (size_t)c0 * Ktot, Zreg,
                                                         idxAll + obase[3], wbAll + obase[3],
                                                         Ychunk, sum, sumsq, nullptr,
                                                         C1, C1, Ktot, 512, 2048, c0, 0);
        k_gemm_dec_acc<<<dim3(M / 128, 2), 256, 0, stream>>>(Ychunk, sum, sumsq,
                                                             glin[3], blin[3], 1.f / M, c0, O,
                                                             Wdec + c0, D, 512, 512, 2048, 256,
                                                             c0 != 0, c0 == 1536, 0, dsum, dsumsq);
      }
    }
  }

  // ---- final dot (decoder BN finalize hoisted in-block) ----
  {
    int M = 32768;
    float* dsum = statsPool + 7 * 2 * 2048;
    float* dsumsq = dsum + 2048;
    k_final_dot2<<<M / 4, 256, 0, stream>>>(D, wdec1, dsum, dsumsq, gdec, bdec, 1.f / M, outp, M);
  }
}

// Round 14
// 703.146 us; speedup vs baseline: 1.0105x; 1.0105x over previous
//
#include <hip/hip_runtime.h>
#include <stdint.h>
#include <stddef.h>

typedef _Float16 half8 __attribute__((ext_vector_type(8)));
typedef _Float16 half4v __attribute__((ext_vector_type(4)));
typedef float f32x4 __attribute__((ext_vector_type(4)));

__device__ __forceinline__ void gload_lds16(const void* g, void* l) {
  __builtin_amdgcn_global_load_lds((const __attribute__((address_space(1))) void*)g,
                                   (__attribute__((address_space(3))) void*)l, 16, 0, 0);
}

// ---------------- merged transpose+cast for all 5 feature tensors ----------------
struct TPack {
  const float* in[5];
  _Float16* out[5];
  int C[5], N[5];
  int cum[6];
};
__global__ __launch_bounds__(256) void k_transpose_all(TPack p) {
  __shared__ float tile[32][33];
  int t = blockIdx.x;
  int ti = 0;
#pragma unroll
  for (int i = 0; i < 5; ++i) if (t >= p.cum[i + 1]) ti = i + 1;
  int lt = t - p.cum[ti];
  int C = p.C[ti], N = p.N[ti];
  const float* in = p.in[ti];
  _Float16* out = p.out[ti];
  int tiles_n = (N + 31) / 32;
  int perb = (C / 32) * tiles_n;
  int b = lt / perb;
  int rem = lt - b * perb;
  int c0 = (rem / tiles_n) * 32;
  int n0 = (rem % tiles_n) * 32;
  int tx = threadIdx.x, ty = threadIdx.y;
#pragma unroll
  for (int j = 0; j < 32; j += 8) {
    int c = c0 + ty + j, n = n0 + tx;
    if (c < C && n < N) tile[ty + j][tx] = in[((size_t)b * C + c) * N + n];
  }
  __syncthreads();
#pragma unroll
  for (int j = 0; j < 32; j += 8) {
    int n = n0 + ty + j, c = c0 + tx;
    if (n < N && c < C) out[((size_t)b * N + n) * C + c] = (_Float16)tile[tx][ty + j];
  }
}

// ---------------- weight cast with zero row/K padding ----------------
__global__ __launch_bounds__(256) void k_cast_pad_w(const float* __restrict__ W,
                                                    _Float16* __restrict__ Wh,
                                                    int O, int K, int Opad, int Kpad) {
  size_t i = ((size_t)blockIdx.x * 256 + threadIdx.x) * 4;
  if (i >= (size_t)Opad * Kpad) return;
  int r = (int)(i / Kpad), k = (int)(i % Kpad);
  half4v v;
#pragma unroll
  for (int j = 0; j < 4; ++j) {
    float f = (r < O && (k + j) < K) ? W[(size_t)r * K + k + j] : 0.f;
    v[j] = (_Float16)f;
  }
  *(half4v*)(Wh + i) = v;
}

// ---------------- merged 3-NN, 4 threads per query (source-split + shfl merge) --------
struct KPack {
  const float* q[4]; const float* p[4];
  int N1[4], S[4];
  int cum[5];
  int obase[4];
};
#define KNN_INS(dd, ii) { float _d = (dd); int _i = (ii); \
  if (_d < d0)      { d2 = d1; i2 = i1; d1 = d0; i1 = i0; d0 = _d; i0 = _i; } \
  else if (_d < d1) { d2 = d1; i2 = i1; d1 = _d; i1 = _i; } \
  else if (_d < d2) { d2 = _d; i2 = _i; } }
__global__ __launch_bounds__(256) void k_knn_all(KPack kp, int4* __restrict__ idxo,
                                                 float4* __restrict__ wo) {
  __shared__ float sp[512 * 3];
  __shared__ float spp[512];
  int t = blockIdx.x;
  int st = 0;
#pragma unroll
  for (int i = 0; i < 4; ++i) if (t >= kp.cum[i + 1]) st = i + 1;
  int lb = t - kp.cum[st];
  int N1 = kp.N1[st], S = kp.S[st];
  int nb = (N1 * 4 + 255) / 256;
  int b = lb / nb;
  int xb = lb - b * nb;
  const float* p = kp.p[st];
  const float* q = kp.q[st];
  for (int i = threadIdx.x; i < S * 3; i += 256) sp[i] = p[(size_t)b * S * 3 + i];
  __syncthreads();
  for (int s = threadIdx.x; s < S; s += 256)
    spp[s] = sp[s * 3] * sp[s * 3] + sp[s * 3 + 1] * sp[s * 3 + 1] + sp[s * 3 + 2] * sp[s * 3 + 2];
  __syncthreads();
  int tt = xb * 256 + threadIdx.x;
  int n = tt >> 2, sub = tt & 3;
  if (n >= N1) return;
  const float* qp = q + ((size_t)b * N1 + n) * 3;
  float qx = qp[0], qy = qp[1], qz = qp[2];
  float qq = qx * qx + qy * qy + qz * qz;
  float d0 = 1e30f, d1 = 1e30f, d2 = 1e30f;
  int i0 = 0, i1 = 0, i2 = 0;
  int Sq = S >> 2;
  int s0 = sub * Sq;
  for (int i = 0; i < Sq; ++i) {
    int s = s0 + i;
    float d = qq + spp[s] - 2.f * (qx * sp[s * 3] + qy * sp[s * 3 + 1] + qz * sp[s * 3 + 2]);
    KNN_INS(d, s);
  }
#pragma unroll
  for (int m = 1; m <= 2; m <<= 1) {
    float rd0 = __shfl_xor(d0, m, 64), rd1 = __shfl_xor(d1, m, 64), rd2 = __shfl_xor(d2, m, 64);
    int   ri0 = __shfl_xor(i0, m, 64), ri1 = __shfl_xor(i1, m, 64), ri2 = __shfl_xor(i2, m, 64);
    KNN_INS(rd0, ri0); KNN_INS(rd1, ri1); KNN_INS(rd2, ri2);
  }
  if (sub == 0) {
    float w0 = 1.f / (d0 + 1e-8f), w1 = 1.f / (d1 + 1e-8f), w2 = 1.f / (d2 + 1e-8f);
    float wsum = w0 + w1 + w2;
    int gi = kp.obase[st] + b * N1 + n;
    idxo[gi] = make_int4(b * S + i0, b * S + i1, b * S + i2, 0);
    wo[gi] = make_float4(w0 / wsum, w1 / wsum, w2 / wsum, 0.f);
  }
}

// ======== XOR-swizzled LDS GEMMs (conflict-free, verified R6-R13) ========

// ---- GEMM, optional INLINE-finalized BN+ReLU on A (from raw sum/sumsq), f16 out ----
__global__ __launch_bounds__(256) void k_gemm_anorm(const _Float16* __restrict__ A,
                                                    const float* __restrict__ sum,
                                                    const float* __restrict__ sumsq,
                                                    const float* __restrict__ g,
                                                    const float* __restrict__ b,
                                                    float invM, int apply_nr,
                                                    const _Float16* __restrict__ W,
                                                    _Float16* __restrict__ Cout,
                                                    int K, int lda, int ldb, int ldc) {
  __shared__ __align__(16) _Float16 lA[128 * 64];
  __shared__ __align__(16) _Float16 lB[128 * 64];
  int tid = threadIdx.x;
  int m0 = blockIdx.x * 128;
  int o0 = blockIdx.y * 128;
  int lane = tid & 63, wv = tid >> 6;
  int wm = (wv & 1) * 64, wo = (wv >> 1) * 64;
  int lr = lane & 15, lq = lane >> 4;
  int trow = tid >> 3;
  int tsegl = (((tid & 7) ^ (trow & 7))) * 8;
  int sw = lr & 7;

  f32x4 acc[4][4];
#pragma unroll
  for (int mi = 0; mi < 4; ++mi)
#pragma unroll
    for (int oi = 0; oi < 4; ++oi)
      acc[mi][oi] = (f32x4){0.f, 0.f, 0.f, 0.f};

  const _Float16* gA = A + (size_t)(m0 + trow) * lda + tsegl;
  const _Float16* gB = W + (size_t)(o0 + trow) * ldb + tsegl;

  for (int k0 = 0; k0 < K; k0 += 64) {
#pragma unroll
    for (int i = 0; i < 4; ++i)
      gload_lds16(gB + (size_t)(32 * i) * ldb + k0, lB + ((size_t)i * 256 + tid) * 8);
    if (apply_nr) {
      float sc[8], sh[8];
#pragma unroll
      for (int j = 0; j < 8; ++j) {
        int c = k0 + tsegl + j;
        float mean = sum[c] * invM;
        float var = sumsq[c] * invM - mean * mean;
        float s = g[c] * rsqrtf(var + 1e-5f);
        sc[j] = s;
        sh[j] = b[c] - mean * s;
      }
#pragma unroll
      for (int i = 0; i < 4; ++i) {
        half8 v = *(const half8*)(gA + (size_t)(32 * i) * lda + k0);
        half8 o;
#pragma unroll
        for (int j = 0; j < 8; ++j)
          o[j] = (_Float16)fmaxf((float)v[j] * sc[j] + sh[j], 0.f);
        *(half8*)&lA[((size_t)i * 256 + tid) * 8] = o;
      }
    } else {
#pragma unroll
      for (int i = 0; i < 4; ++i)
        gload_lds16(gA + (size_t)(32 * i) * lda + k0, lA + ((size_t)i * 256 + tid) * 8);
    }
    __syncthreads();
#pragma unroll
    for (int ks = 0; ks < 64; ks += 32) {
      half8 af[4], bf[4];
#pragma unroll
      for (int mi = 0; mi < 4; ++mi)
        af[mi] = *(const half8*)&lA[(wm + mi * 16 + lr) * 64 + ((((ks >> 3) + lq) ^ sw)) * 8];
#pragma unroll
      for (int oi = 0; oi < 4; ++oi)
        bf[oi] = *(const half8*)&lB[(wo + oi * 16 + lr) * 64 + ((((ks >> 3) + lq) ^ sw)) * 8];
#pragma unroll
      for (int mi = 0; mi < 4; ++mi)
#pragma unroll
        for (int oi = 0; oi < 4; ++oi)
          acc[mi][oi] = __builtin_amdgcn_mfma_f32_16x16x32_f16(af[mi], bf[oi], acc[mi][oi], 0, 0, 0);
    }
    __syncthreads();
  }

#pragma unroll
  for (int mi = 0; mi < 4; ++mi)
#pragma unroll
    for (int oi = 0; oi < 4; ++oi) {
      int col = o0 + wo + oi * 16 + lr;
      int rowb = m0 + wm + mi * 16 + lq * 4;
#pragma unroll
      for (int r = 0; r < 4; ++r)
        Cout[(size_t)(rowb + r) * ldc + col] = (_Float16)acc[mi][oi][r];
    }
}

// ---- FUSED 128x128: Y = skip.Wskip^T + interp(Z); vectorized epilogue; opt XCD swizzle ----
__global__ __launch_bounds__(256) void k_gemm_yis(const _Float16* __restrict__ A,
                                                  const _Float16* __restrict__ W,
                                                  const _Float16* __restrict__ Z,
                                                  const int4* __restrict__ idxb,
                                                  const float4* __restrict__ wb,
                                                  _Float16* __restrict__ Y,
                                                  float* __restrict__ sum,
                                                  float* __restrict__ sumsq,
                                                  int K, int lda, int ldb, int ldy,
                                                  int ldz, int zcol0, int swz) {
  __shared__ __align__(16) _Float16 lsm[2 * 128 * 64];
  __shared__ int4 sIdx[128];
  __shared__ float4 sWt[128];
  __shared__ float sStat[256];
  _Float16* lA = lsm;
  _Float16* lB = lsm + 128 * 64;
  int tid = threadIdx.x;
  int m0, o0;
  if (swz) {
    // XCD-aware (R10-verified: FETCH 120->57MB)
    int bid = blockIdx.y * gridDim.x + blockIdx.x;
    int o = (bid & 7) + ((bid >> 11) << 3);
    int m = (bid >> 3) & 255;
    m0 = m * 128; o0 = o * 128;
  } else {
    m0 = blockIdx.x * 128; o0 = blockIdx.y * 128;
  }
  if (tid < 128) {
    sIdx[tid] = idxb[m0 + tid];
    sWt[tid] = wb[m0 + tid];
  }
  sStat[tid] = 0.f;
  int lane = tid & 63, wv = tid >> 6;
  int wm = (wv & 1) * 64, wo = (wv >> 1) * 64;
  int lr = lane & 15, lq = lane >> 4;
  int trow = tid >> 3;
  int tsegl = (((tid & 7) ^ (trow & 7))) * 8;
  int sw = lr & 7;

  f32x4 acc[4][4];
#pragma unroll
  for (int mi = 0; mi < 4; ++mi)
#pragma unroll
    for (int oi = 0; oi < 4; ++oi)
      acc[mi][oi] = (f32x4){0.f, 0.f, 0.f, 0.f};

  const _Float16* gA = A + (size_t)(m0 + trow) * lda + tsegl;
  const _Float16* gB = W + (size_t)(o0 + trow) * ldb + tsegl;

  for (int k0 = 0; k0 < K; k0 += 64) {
#pragma unroll
    for (int i = 0; i < 4; ++i) {
      gload_lds16(gA + (size_t)(32 * i) * lda + k0, lA + ((size_t)i * 256 + tid) * 8);
      gload_lds16(gB + (size_t)(32 * i) * ldb + k0, lB + ((size_t)i * 256 + tid) * 8);
    }
    __syncthreads();
#pragma unroll
    for (int ks = 0; ks < 64; ks += 32) {
      half8 af[4], bf[4];
#pragma unroll
      for (int mi = 0; mi < 4; ++mi)
        af[mi] = *(const half8*)&lA[(wm + mi * 16 + lr) * 64 + ((((ks >> 3) + lq) ^ sw)) * 8];
#pragma unroll
      for (int oi = 0; oi < 4; ++oi)
        bf[oi] = *(const half8*)&lB[(wo + oi * 16 + lr) * 64 + ((((ks >> 3) + lq) ^ sw)) * 8];
#pragma unroll
      for (int mi = 0; mi < 4; ++mi)
#pragma unroll
        for (int oi = 0; oi < 4; ++oi)
          acc[mi][oi] = __builtin_amdgcn_mfma_f32_16x16x32_f16(af[mi], bf[oi], acc[mi][oi], 0, 0, 0);
    }
    __syncthreads();
  }

#pragma unroll
  for (int mi = 0; mi < 4; ++mi)
#pragma unroll
    for (int oi = 0; oi < 4; ++oi)
#pragma unroll
      for (int r = 0; r < 4; ++r)
        lsm[(wm + mi * 16 + lq * 4 + r) * 128 + (wo + oi * 16 + lr)] = (_Float16)acc[mi][oi][r];
  __syncthreads();

  int tcol = (tid & 15) * 8;
  int rbase = tid >> 4;
  float s8[8], q8[8];
#pragma unroll
  for (int j = 0; j < 8; ++j) { s8[j] = 0.f; q8[j] = 0.f; }
#pragma unroll
  for (int i = 0; i < 8; ++i) {
    int row = rbase + i * 16;
    int4 id = sIdx[row];
    float4 w = sWt[row];
    half8 y = *(half8*)&lsm[row * 128 + tcol];
    int zc = zcol0 + o0 + tcol;
    half8 a  = *(const half8*)&Z[(size_t)id.x * ldz + zc];
    half8 b2 = *(const half8*)&Z[(size_t)id.y * ldz + zc];
    half8 c2 = *(const half8*)&Z[(size_t)id.z * ldz + zc];
    half8 o;
#pragma unroll
    for (int j = 0; j < 8; ++j) {
      float v = (float)y[j] + w.x * (float)a[j] + w.y * (float)b2[j] + w.z * (float)c2[j];
      o[j] = (_Float16)v;
      s8[j] += v; q8[j] += v * v;
    }
    *(half8*)&Y[(size_t)(m0 + row) * ldy + o0 + tcol] = o;
  }
#pragma unroll
  for (int j = 0; j < 8; ++j) {
    atomicAdd(&sStat[tcol + j], s8[j]);
    atomicAdd(&sStat[128 + tcol + j], q8[j]);
  }
  __syncthreads();
  if (tid < 128) {
    atomicAdd(&sum[o0 + tid], sStat[tid]);
    atomicAdd(&sumsq[o0 + tid], sStat[128 + tid]);
  }
}

// ---- decoder GEMM: folded BN-finalize + normrelu on A, f32 out/acc into D,
//      optional fused D-stats; swz pairs (m,o=0)/(m,o=1) on one XCD for Y3 L2 reuse ----
__global__ __launch_bounds__(256) void k_gemm_dec_acc(const _Float16* __restrict__ A,
                                                      const float* __restrict__ sumc,
                                                      const float* __restrict__ sumsqc,
                                                      const float* __restrict__ g,
                                                      const float* __restrict__ b,
                                                      float invM, int c0, int Oglob,
                                                      const _Float16* __restrict__ W,
                                                      float* __restrict__ D,
                                                      int K, int lda, int ldb, int ldc,
                                                      int accum, int do_stats, int swz,
                                                      float* __restrict__ dsum,
                                                      float* __restrict__ dsumsq) {
  __shared__ __align__(16) _Float16 lA[128 * 64];
  __shared__ __align__(16) _Float16 lB[128 * 64];
  __shared__ float sScale[2048];
  __shared__ float sShift[2048];
  __shared__ float sStat[256];
  int tid = threadIdx.x;
  int m0, o0;
  if (swz) {
    int bid = blockIdx.y * gridDim.x + blockIdx.x;
    int mlow = bid & 7, oo = (bid >> 3) & 1, mhigh = bid >> 4;
    m0 = (mhigh * 8 + mlow) * 128;
    o0 = oo * 128;
  } else {
    m0 = blockIdx.x * 128; o0 = blockIdx.y * 128;
  }
  for (int c = tid; c < K; c += 256) {
    int gc = c0 + c;
    float sc = 0.f, sh = 0.f;
    if (gc < Oglob) {
      float mean = sumc[c] * invM;
      float var = sumsqc[c] * invM - mean * mean;
      sc = g[gc] * rsqrtf(var + 1e-5f);
      sh = b[gc] - mean * sc;
    }
    sScale[c] = sc; sShift[c] = sh;
  }
  sStat[tid] = 0.f;
  __syncthreads();

  int lane = tid & 63, wv = tid >> 6;
  int wm = (wv & 1) * 64, wo = (wv >> 1) * 64;
  int lr = lane & 15, lq = lane >> 4;
  int trow = tid >> 3;
  int tsegl = (((tid & 7) ^ (trow & 7))) * 8;
  int sw = lr & 7;

  f32x4 acc[4][4];
#pragma unroll
  for (int mi = 0; mi < 4; ++mi)
#pragma unroll
    for (int oi = 0; oi < 4; ++oi)
      acc[mi][oi] = (f32x4){0.f, 0.f, 0.f, 0.f};

  const _Float16* gA = A + (size_t)(m0 + trow) * lda + tsegl;
  const _Float16* gB = W + (size_t)(o0 + trow) * ldb + tsegl;

  for (int k0 = 0; k0 < K; k0 += 64) {
#pragma unroll
    for (int i = 0; i < 4; ++i)
      gload_lds16(gB + (size_t)(32 * i) * ldb + k0, lB + ((size_t)i * 256 + tid) * 8);
    float sc[8], sh[8];
#pragma unroll
    for (int j = 0; j < 8; ++j) { sc[j] = sScale[k0 + tsegl + j]; sh[j] = sShift[k0 + tsegl + j]; }
#pragma unroll
    for (int i = 0; i < 4; ++i) {
      half8 v = *(const half8*)(gA + (size_t)(32 * i) * lda + k0);
      half8 o;
#pragma unroll
      for (int j = 0; j < 8; ++j)
        o[j] = (_Float16)fmaxf((float)v[j] * sc[j] + sh[j], 0.f);
      *(half8*)&lA[((size_t)i * 256 + tid) * 8] = o;
    }
    __syncthreads();
#pragma unroll
    for (int ks = 0; ks < 64; ks += 32) {
      half8 af[4], bf[4];
#pragma unroll
      for (int mi = 0; mi < 4; ++mi)
        af[mi] = *(const half8*)&lA[(wm + mi * 16 + lr) * 64 + ((((ks >> 3) + lq) ^ sw)) * 8];
#pragma unroll
      for (int oi = 0; oi < 4; ++oi)
        bf[oi] = *(const half8*)&lB[(wo + oi * 16 + lr) * 64 + ((((ks >> 3) + lq) ^ sw)) * 8];
#pragma unroll
      for (int mi = 0; mi < 4; ++mi)
#pragma unroll
        for (int oi = 0; oi < 4; ++oi)
          acc[mi][oi] = __builtin_amdgcn_mfma_f32_16x16x32_f16(af[mi], bf[oi], acc[mi][oi], 0, 0, 0);
    }
    __syncthreads();
  }

  float ps[4], pq[4];
#pragma unroll
  for (int oi = 0; oi < 4; ++oi) { ps[oi] = 0.f; pq[oi] = 0.f; }
#pragma unroll
  for (int mi = 0; mi < 4; ++mi)
#pragma unroll
    for (int oi = 0; oi < 4; ++oi) {
      int col = o0 + wo + oi * 16 + lr;
      int rowb = m0 + wm + mi * 16 + lq * 4;
#pragma unroll
      for (int r = 0; r < 4; ++r) {
        size_t idx = (size_t)(rowb + r) * ldc + col;
        float v = acc[mi][oi][r];
        if (accum) v += D[idx];
        D[idx] = v;
        if (do_stats) { ps[oi] += v; pq[oi] += v * v; }
      }
    }
  if (do_stats) {
#pragma unroll
    for (int oi = 0; oi < 4; ++oi) {
      int tc = wo + oi * 16 + lr;
      atomicAdd(&sStat[tc], ps[oi]);
      atomicAdd(&sStat[128 + tc], pq[oi]);
    }
    __syncthreads();
    if (tid < 128) {
      atomicAdd(&dsum[o0 + tid], sStat[tid]);
      atomicAdd(&dsumsq[o0 + tid], sStat[128 + tid]);
    }
  }
}

// ---------------- final dot; BN finalize hoisted into LDS once per block ----------------
__global__ __launch_bounds__(256) void k_final_dot2(const float* __restrict__ H,
                                                    const float* __restrict__ w,
                                                    const float* __restrict__ dsum,
                                                    const float* __restrict__ dsumsq,
                                                    const float* __restrict__ g,
                                                    const float* __restrict__ b,
                                                    float invM,
                                                    float* __restrict__ out, int Mtot) {
  __shared__ float sSc[256], sSh[256];
  int tid = threadIdx.x;
  {
    int c = tid;
    float mean = dsum[c] * invM;
    float var = dsumsq[c] * invM - mean * mean;
    float sc = g[c] * rsqrtf(var + 1e-5f);
    sSc[c] = sc;
    sSh[c] = b[c] - mean * sc;
  }
  __syncthreads();
  int lane = tid & 63, wv = tid >> 6;
  int r = blockIdx.x * 4 + wv;
  if (r >= Mtot) return;
  const float* h = H + (size_t)r * 256;
  float s = 0.f;
  for (int c = lane; c < 256; c += 64)
    s += fmaxf(h[c] * sSc[c] + sSh[c], 0.f) * w[c];
#pragma unroll
  for (int o = 32; o > 0; o >>= 1) s += __shfl_down(s, o, 64);
  if (lane == 0) out[r] = s;
}

extern "C" void kernel_launch(void* const* d_in, const int* in_sizes, int n_in,
                              void* d_out, int out_size, void* d_ws, size_t ws_size,
                              hipStream_t stream) {
  (void)in_sizes; (void)n_in; (void)out_size;
  const int B = 16;
  const float* xyzs[5]; const float* xs[5];
  for (int i = 0; i < 5; ++i) { xyzs[i] = (const float*)d_in[2 * i]; xs[i] = (const float*)d_in[2 * i + 1]; }
  const float* wlin[4] = {(const float*)d_in[10], (const float*)d_in[13], (const float*)d_in[16], (const float*)d_in[19]};
  const float* glin[4] = {(const float*)d_in[11], (const float*)d_in[14], (const float*)d_in[17], (const float*)d_in[20]};
  const float* blin[4] = {(const float*)d_in[12], (const float*)d_in[15], (const float*)d_in[18], (const float*)d_in[21]};
  const float* wdec0 = (const float*)d_in[22];
  const float* gdec  = (const float*)d_in[23];
  const float* bdec  = (const float*)d_in[24];
  const float* wdec1 = (const float*)d_in[25];
  float* outp = (float*)d_out;

  const int ch[5] = {64, 128, 256, 512, 1024};
  const int np[5] = {2048, 512, 128, 32, 8};

  char* base = (char*)d_ws;
  size_t off = 0;
  auto alloc = [&](size_t bytes) -> char* {
    char* p = base + off;
    off += (bytes + 255) & ~(size_t)255;
    return p;
  };

  _Float16* Wbuf = (_Float16*)alloc((size_t)2048 * 1984 * 2);
  _Float16* Wdec = (_Float16*)alloc((size_t)256 * 2048 * 2);
  _Float16* tT[5];
  for (int i = 0; i < 5; ++i) tT[i] = (_Float16*)alloc((size_t)B * np[i] * ch[i] * 2);
  int4* idxAll = (int4*)alloc(43520 * sizeof(int4));
  float4* wbAll = (float4*)alloc(43520 * sizeof(float4));
  float* statsPool = (float*)alloc(8 * 2 * 2048 * sizeof(float));
  _Float16* Zreg = (_Float16*)alloc((size_t)8192 * 2048 * 2);
  float* D = (float*)alloc((size_t)32768 * 256 * 4);
  size_t ybytes_chunk = 40370176;
  size_t ybytes_full = (size_t)32768 * 2048 * 2;
  int use_full = (ws_size >= off + ybytes_full + 256);
  char* Yreg = alloc(use_full ? ybytes_full : ybytes_chunk);
  _Float16* Y0 = (_Float16*)Yreg;
  _Float16* Y1 = (_Float16*)(Yreg + (size_t)512 * 1536 * 2);
  _Float16* Y2 = (_Float16*)(Yreg + (size_t)(512 * 1536 + 2048 * 1792) * 2);
  _Float16* Ychunk = (_Float16*)Yreg;
  _Float16* Y3full = (_Float16*)Yreg;
  if (off > ws_size) return;

  hipMemsetAsync(statsPool, 0, 8 * 2 * 2048 * sizeof(float), stream);

  // merged transpose
  {
    TPack p;
    int cum = 0;
    for (int i = 0; i < 5; ++i) {
      p.in[i] = xs[i]; p.out[i] = tT[i]; p.C[i] = ch[i]; p.N[i] = np[i];
      p.cum[i] = cum;
      cum += (ch[i] / 32) * ((np[i] + 31) / 32) * B;
    }
    p.cum[5] = cum;
    k_transpose_all<<<cum, dim3(32, 8), 0, stream>>>(p);
  }
  {
    size_t tot4 = (size_t)256 * 2048 / 4;
    k_cast_pad_w<<<dim3((unsigned)((tot4 + 255) / 256)), 256, 0, stream>>>(wdec0, Wdec, 256, 1984, 256, 2048);
  }

  const int N1s[4] = {32, 128, 512, 2048};
  const int Ss[4]  = {8, 32, 128, 512};
  const int C1s[4] = {512, 256, 128, 64};
  const int C2s[4] = {1024, 1536, 1792, 1920};
  const int Os[4]  = {1536, 1792, 1920, 1984};
  const int obase[4] = {0, 512, 2560, 10752};
  _Float16* Ys[3] = {Y0, Y1, Y2};

  // merged kNN (4 threads per query)
  {
    KPack kp;
    int cum = 0;
    for (int st = 0; st < 4; ++st) {
      kp.q[st] = xyzs[3 - st]; kp.p[st] = xyzs[4 - st];
      kp.N1[st] = N1s[st]; kp.S[st] = Ss[st];
      kp.cum[st] = cum;
      cum += ((N1s[st] * 4 + 255) / 256) * B;
      kp.obase[st] = obase[st];
    }
    kp.cum[4] = cum;
    k_knn_all<<<cum, 256, 0, stream>>>(kp, idxAll, wbAll);
  }

  // ---- stages 0..2 (inline-finalized anorm: no k_bn_finalize dispatches) ----
  for (int st = 0; st < 3; ++st) {
    int N1 = N1s[st], C1 = C1s[st], C2 = C2s[st], O = Os[st];
    int Ktot = C1 + C2;
    int M = B * N1, Msrc = B * Ss[st];
    const _Float16* H = (st == 0) ? tT[4] : Ys[st - 1];
    _Float16* Y = Ys[st];
    float* sum = statsPool + st * 2 * 2048;
    float* sumsq = sum + 2048;

    size_t wt = (size_t)O * Ktot / 4;
    k_cast_pad_w<<<(unsigned)((wt + 255) / 256), 256, 0, stream>>>(wlin[st], Wbuf, O, Ktot, O, Ktot);

    // prev-stage stats (slot st-1), invM = 1/Msrc rows of H
    const float* psum = (st == 0) ? statsPool : statsPool + (st - 1) * 2 * 2048;
    const float* psumsq = psum + 2048;
    const float* pg = (st == 0) ? glin[0] : glin[st - 1];
    const float* pb = (st == 0) ? blin[0] : blin[st - 1];
    k_gemm_anorm<<<dim3(Msrc / 128, O / 128), 256, 0, stream>>>(H, psum, psumsq, pg, pb,
                                                                1.f / Msrc, st != 0,
                                                                Wbuf + C1, Zreg, C2, C2, Ktot, O);
    k_gemm_yis<<<dim3(M / 128, O / 128), 256, 0, stream>>>(tT[3 - st], Wbuf, Zreg,
                                                           idxAll + obase[st], wbAll + obase[st],
                                                           Y, sum, sumsq,
                                                           C1, C1, Ktot, O, O, 0, 0);
  }

  // ---- stage 3 ----
  {
    int C1 = 64, C2 = 1920, O = 1984, M = 32768, Msrc = 8192;
    int Ktot = 1984;
    size_t wt = (size_t)2048 * Ktot / 4;
    k_cast_pad_w<<<(unsigned)((wt + 255) / 256), 256, 0, stream>>>(wlin[3], Wbuf, O, Ktot, 2048, Ktot);

    // Z3 = normrelu(Y2).Wint^T  — inline finalize from stage-2 stats
    float* s2 = statsPool + 2 * 2 * 2048;
    k_gemm_anorm<<<dim3(Msrc / 128, 16), 256, 0, stream>>>(Y2, s2, s2 + 2048, glin[2], blin[2],
                                                           1.f / Msrc, 1,
                                                           Wbuf + C1, Zreg, C2, C2, Ktot, 2048);

    float* dsum = statsPool + 7 * 2 * 2048;
    float* dsumsq = dsum + 2048;
    if (use_full) {
      float* sum = statsPool + 3 * 2 * 2048;
      float* sumsq = sum + 2048;
      // Y3 (32768 x 2048), 128x128 tiles, XCD-swizzled (R10-verified)
      k_gemm_yis<<<dim3(256, 16), 256, 0, stream>>>(tT[0], Wbuf, Zreg,
                                                    idxAll + obase[3], wbAll + obase[3],
                                                    Y3full, sum, sumsq,
                                                    C1, C1, Ktot, 2048, 2048, 0, 1);
      // D = normrelu(Y3).Wdec^T, K=2048, pair-swizzled, fused D-stats
      k_gemm_dec_acc<<<dim3(256, 2), 256, 0, stream>>>(Y3full, sum, sumsq,
                                                       glin[3], blin[3], 1.f / M, 0, O,
                                                       Wdec, D, 2048, 2048, 2048, 256,
                                                       0, 1, 1, dsum, dsumsq);
    } else {
      for (int c0 = 0; c0 < 2048; c0 += 512) {
        float* sum = statsPool + (3 + c0 / 512) * 2 * 2048;
        float* sumsq = sum + 2048;
        k_gemm_yis<<<dim3(M / 128, 4), 256, 0, stream>>>(tT[0], Wbuf + (size_t)c0 * Ktot, Zreg,
                                                         idxAll + obase[3], wbAll + obase[3],
                                                         Ychunk, sum, sumsq,
                                                         C1, C1, Ktot, 512, 2048, c0, 0);
        k_gemm_dec_acc<<<dim3(M / 128, 2), 256, 0, stream>>>(Ychunk, sum, sumsq,
                                                             glin[3], blin[3], 1.f / M, c0, O,
                                                             Wdec + c0, D, 512, 512, 2048, 256,
                                                             c0 != 0, c0 == 1536, 0, dsum, dsumsq);
      }
    }
  }

  // ---- final dot (decoder BN finalize hoisted in-block) ----
  {
    int M = 32768;
    float* dsum = statsPool + 7 * 2 * 2048;
    float* dsumsq = dsum + 2048;
    k_final_dot2<<<M / 4, 256, 0, stream>>>(D, wdec1, dsum, dsumsq, gdec, bdec, 1.f / M, outp, M);
  }
}

// Round 15
// 659.197 us; speedup vs baseline: 1.0779x; 1.0667x over previous
//
#include <hip/hip_runtime.h>
#include <stdint.h>
#include <stddef.h>

typedef _Float16 half8 __attribute__((ext_vector_type(8)));
typedef _Float16 half4v __attribute__((ext_vector_type(4)));
typedef float f32x4 __attribute__((ext_vector_type(4)));

__device__ __forceinline__ void gload_lds16(const void* g, void* l) {
  __builtin_amdgcn_global_load_lds((const __attribute__((address_space(1))) void*)g,
                                   (__attribute__((address_space(3))) void*)l, 16, 0, 0);
}

// ---------------- merged transpose+cast for all 5 feature tensors ----------------
struct TPack {
  const float* in[5];
  _Float16* out[5];
  int C[5], N[5];
  int cum[6];
};
__global__ __launch_bounds__(256) void k_transpose_all(TPack p) {
  __shared__ float tile[32][33];
  int t = blockIdx.x;
  int ti = 0;
#pragma unroll
  for (int i = 0; i < 5; ++i) if (t >= p.cum[i + 1]) ti = i + 1;
  int lt = t - p.cum[ti];
  int C = p.C[ti], N = p.N[ti];
  const float* in = p.in[ti];
  _Float16* out = p.out[ti];
  int tiles_n = (N + 31) / 32;
  int perb = (C / 32) * tiles_n;
  int b = lt / perb;
  int rem = lt - b * perb;
  int c0 = (rem / tiles_n) * 32;
  int n0 = (rem % tiles_n) * 32;
  int tx = threadIdx.x, ty = threadIdx.y;
#pragma unroll
  for (int j = 0; j < 32; j += 8) {
    int c = c0 + ty + j, n = n0 + tx;
    if (c < C && n < N) tile[ty + j][tx] = in[((size_t)b * C + c) * N + n];
  }
  __syncthreads();
#pragma unroll
  for (int j = 0; j < 32; j += 8) {
    int n = n0 + ty + j, c = c0 + tx;
    if (n < N && c < C) out[((size_t)b * N + n) * C + c] = (_Float16)tile[tx][ty + j];
  }
}

// ---------------- weight cast with zero row/K padding ----------------
__global__ __launch_bounds__(256) void k_cast_pad_w(const float* __restrict__ W,
                                                    _Float16* __restrict__ Wh,
                                                    int O, int K, int Opad, int Kpad) {
  size_t i = ((size_t)blockIdx.x * 256 + threadIdx.x) * 4;
  if (i >= (size_t)Opad * Kpad) return;
  int r = (int)(i / Kpad), k = (int)(i % Kpad);
  half4v v;
#pragma unroll
  for (int j = 0; j < 4; ++j) {
    float f = (r < O && (k + j) < K) ? W[(size_t)r * K + k + j] : 0.f;
    v[j] = (_Float16)f;
  }
  *(half4v*)(Wh + i) = v;
}

// ---------------- merged 3-NN, 4 threads per query (source-split + shfl merge) --------
struct KPack {
  const float* q[4]; const float* p[4];
  int N1[4], S[4];
  int cum[5];
  int obase[4];
};
#define KNN_INS(dd, ii) { float _d = (dd); int _i = (ii); \
  if (_d < d0)      { d2 = d1; i2 = i1; d1 = d0; i1 = i0; d0 = _d; i0 = _i; } \
  else if (_d < d1) { d2 = d1; i2 = i1; d1 = _d; i1 = _i; } \
  else if (_d < d2) { d2 = _d; i2 = _i; } }
__global__ __launch_bounds__(256) void k_knn_all(KPack kp, int4* __restrict__ idxo,
                                                 float4* __restrict__ wo) {
  __shared__ float sp[512 * 3];
  __shared__ float spp[512];
  int t = blockIdx.x;
  int st = 0;
#pragma unroll
  for (int i = 0; i < 4; ++i) if (t >= kp.cum[i + 1]) st = i + 1;
  int lb = t - kp.cum[st];
  int N1 = kp.N1[st], S = kp.S[st];
  int nb = (N1 * 4 + 255) / 256;
  int b = lb / nb;
  int xb = lb - b * nb;
  const float* p = kp.p[st];
  const float* q = kp.q[st];
  for (int i = threadIdx.x; i < S * 3; i += 256) sp[i] = p[(size_t)b * S * 3 + i];
  __syncthreads();
  for (int s = threadIdx.x; s < S; s += 256)
    spp[s] = sp[s * 3] * sp[s * 3] + sp[s * 3 + 1] * sp[s * 3 + 1] + sp[s * 3 + 2] * sp[s * 3 + 2];
  __syncthreads();
  int tt = xb * 256 + threadIdx.x;
  int n = tt >> 2, sub = tt & 3;
  if (n >= N1) return;
  const float* qp = q + ((size_t)b * N1 + n) * 3;
  float qx = qp[0], qy = qp[1], qz = qp[2];
  float qq = qx * qx + qy * qy + qz * qz;
  float d0 = 1e30f, d1 = 1e30f, d2 = 1e30f;
  int i0 = 0, i1 = 0, i2 = 0;
  int Sq = S >> 2;
  int s0 = sub * Sq;
  for (int i = 0; i < Sq; ++i) {
    int s = s0 + i;
    float d = qq + spp[s] - 2.f * (qx * sp[s * 3] + qy * sp[s * 3 + 1] + qz * sp[s * 3 + 2]);
    KNN_INS(d, s);
  }
#pragma unroll
  for (int m = 1; m <= 2; m <<= 1) {
    float rd0 = __shfl_xor(d0, m, 64), rd1 = __shfl_xor(d1, m, 64), rd2 = __shfl_xor(d2, m, 64);
    int   ri0 = __shfl_xor(i0, m, 64), ri1 = __shfl_xor(i1, m, 64), ri2 = __shfl_xor(i2, m, 64);
    KNN_INS(rd0, ri0); KNN_INS(rd1, ri1); KNN_INS(rd2, ri2);
  }
  if (sub == 0) {
    float w0 = 1.f / (d0 + 1e-8f), w1 = 1.f / (d1 + 1e-8f), w2 = 1.f / (d2 + 1e-8f);
    float wsum = w0 + w1 + w2;
    int gi = kp.obase[st] + b * N1 + n;
    idxo[gi] = make_int4(b * S + i0, b * S + i1, b * S + i2, 0);
    wo[gi] = make_float4(w0 / wsum, w1 / wsum, w2 / wsum, 0.f);
  }
}

// ---------------- elementwise BN normalize + ReLU, f16 in place ----------------
__global__ __launch_bounds__(256) void k_bn_norm(_Float16* __restrict__ G,
                                                 const float* __restrict__ scale,
                                                 const float* __restrict__ shiftv,
                                                 size_t total8, int ld) {
  size_t i = (size_t)blockIdx.x * 256 + threadIdx.x;
  if (i >= total8) return;
  half8 v = *(half8*)&G[i * 8];
  int c0 = (int)((i * 8) % (size_t)ld);
#pragma unroll
  for (int j = 0; j < 8; ++j) {
    float f = (float)v[j] * scale[c0 + j] + shiftv[c0 + j];
    v[j] = (_Float16)fmaxf(f, 0.f);
  }
  *(half8*)&G[i * 8] = v;
}

__global__ __launch_bounds__(256) void k_bn_finalize(const float* __restrict__ sum,
                                                     const float* __restrict__ sumsq,
                                                     const float* __restrict__ g, const float* __restrict__ b,
                                                     float* __restrict__ scale, float* __restrict__ shiftv,
                                                     int O, int Opad, float invM) {
  int c = blockIdx.x * 256 + threadIdx.x;
  if (c >= Opad) return;
  if (c < O) {
    float mean = sum[c] * invM;
    float var = sumsq[c] * invM - mean * mean;
    float sc = g[c] * rsqrtf(var + 1e-5f);
    scale[c] = sc;
    shiftv[c] = b[c] - mean * sc;
  } else {
    scale[c] = 0.f;
    shiftv[c] = 0.f;
  }
}

// ======== XOR-swizzled LDS GEMMs (conflict-free, verified R6-R14) ========

// ---------------- GEMM, optional fused BN+ReLU on A (precomputed scale/shift), f16 out ----
__global__ __launch_bounds__(256) void k_gemm_anorm(const _Float16* __restrict__ A,
                                                    const float* __restrict__ scale,
                                                    const float* __restrict__ shift,
                                                    int apply_nr,
                                                    const _Float16* __restrict__ W,
                                                    _Float16* __restrict__ Cout,
                                                    int K, int lda, int ldb, int ldc) {
  __shared__ __align__(16) _Float16 lA[128 * 64];
  __shared__ __align__(16) _Float16 lB[128 * 64];
  int tid = threadIdx.x;
  int m0 = blockIdx.x * 128;
  int o0 = blockIdx.y * 128;
  int lane = tid & 63, wv = tid >> 6;
  int wm = (wv & 1) * 64, wo = (wv >> 1) * 64;
  int lr = lane & 15, lq = lane >> 4;
  int trow = tid >> 3;
  int tsegl = (((tid & 7) ^ (trow & 7))) * 8;
  int sw = lr & 7;

  f32x4 acc[4][4];
#pragma unroll
  for (int mi = 0; mi < 4; ++mi)
#pragma unroll
    for (int oi = 0; oi < 4; ++oi)
      acc[mi][oi] = (f32x4){0.f, 0.f, 0.f, 0.f};

  const _Float16* gA = A + (size_t)(m0 + trow) * lda + tsegl;
  const _Float16* gB = W + (size_t)(o0 + trow) * ldb + tsegl;

  for (int k0 = 0; k0 < K; k0 += 64) {
#pragma unroll
    for (int i = 0; i < 4; ++i)
      gload_lds16(gB + (size_t)(32 * i) * ldb + k0, lB + ((size_t)i * 256 + tid) * 8);
    if (apply_nr) {
      float sc[8], sh[8];
#pragma unroll
      for (int j = 0; j < 8; ++j) { sc[j] = scale[k0 + tsegl + j]; sh[j] = shift[k0 + tsegl + j]; }
#pragma unroll
      for (int i = 0; i < 4; ++i) {
        half8 v = *(const half8*)(gA + (size_t)(32 * i) * lda + k0);
        half8 o;
#pragma unroll
        for (int j = 0; j < 8; ++j)
          o[j] = (_Float16)fmaxf((float)v[j] * sc[j] + sh[j], 0.f);
        *(half8*)&lA[((size_t)i * 256 + tid) * 8] = o;
      }
    } else {
#pragma unroll
      for (int i = 0; i < 4; ++i)
        gload_lds16(gA + (size_t)(32 * i) * lda + k0, lA + ((size_t)i * 256 + tid) * 8);
    }
    __syncthreads();
#pragma unroll
    for (int ks = 0; ks < 64; ks += 32) {
      half8 af[4], bf[4];
#pragma unroll
      for (int mi = 0; mi < 4; ++mi)
        af[mi] = *(const half8*)&lA[(wm + mi * 16 + lr) * 64 + ((((ks >> 3) + lq) ^ sw)) * 8];
#pragma unroll
      for (int oi = 0; oi < 4; ++oi)
        bf[oi] = *(const half8*)&lB[(wo + oi * 16 + lr) * 64 + ((((ks >> 3) + lq) ^ sw)) * 8];
#pragma unroll
      for (int mi = 0; mi < 4; ++mi)
#pragma unroll
        for (int oi = 0; oi < 4; ++oi)
          acc[mi][oi] = __builtin_amdgcn_mfma_f32_16x16x32_f16(af[mi], bf[oi], acc[mi][oi], 0, 0, 0);
    }
    __syncthreads();
  }

#pragma unroll
  for (int mi = 0; mi < 4; ++mi)
#pragma unroll
    for (int oi = 0; oi < 4; ++oi) {
      int col = o0 + wo + oi * 16 + lr;
      int rowb = m0 + wm + mi * 16 + lq * 4;
#pragma unroll
      for (int r = 0; r < 4; ++r)
        Cout[(size_t)(rowb + r) * ldc + col] = (_Float16)acc[mi][oi][r];
    }
}

// ---- FUSED 128x128: Y = skip.Wskip^T + interp(Z); vectorized epilogue; opt XCD swizzle ----
__global__ __launch_bounds__(256) void k_gemm_yis(const _Float16* __restrict__ A,
                                                  const _Float16* __restrict__ W,
                                                  const _Float16* __restrict__ Z,
                                                  const int4* __restrict__ idxb,
                                                  const float4* __restrict__ wb,
                                                  _Float16* __restrict__ Y,
                                                  float* __restrict__ sum,
                                                  float* __restrict__ sumsq,
                                                  int K, int lda, int ldb, int ldy,
                                                  int ldz, int zcol0, int swz) {
  __shared__ __align__(16) _Float16 lsm[2 * 128 * 64];
  __shared__ int4 sIdx[128];
  __shared__ float4 sWt[128];
  __shared__ float sStat[256];
  _Float16* lA = lsm;
  _Float16* lB = lsm + 128 * 64;
  int tid = threadIdx.x;
  int m0, o0;
  if (swz) {
    // XCD-aware (R10-verified: FETCH 120->57MB): consecutive bids -> different o-tiles;
    // blocks on one XCD scan m with fixed o -> 2MB Z col-slice stays L2-resident.
    int bid = blockIdx.y * gridDim.x + blockIdx.x;
    int o = (bid & 7) + ((bid >> 11) << 3);
    int m = (bid >> 3) & 255;
    m0 = m * 128; o0 = o * 128;
  } else {
    m0 = blockIdx.x * 128; o0 = blockIdx.y * 128;
  }
  if (tid < 128) {
    sIdx[tid] = idxb[m0 + tid];
    sWt[tid] = wb[m0 + tid];
  }
  sStat[tid] = 0.f;
  int lane = tid & 63, wv = tid >> 6;
  int wm = (wv & 1) * 64, wo = (wv >> 1) * 64;
  int lr = lane & 15, lq = lane >> 4;
  int trow = tid >> 3;
  int tsegl = (((tid & 7) ^ (trow & 7))) * 8;
  int sw = lr & 7;

  f32x4 acc[4][4];
#pragma unroll
  for (int mi = 0; mi < 4; ++mi)
#pragma unroll
    for (int oi = 0; oi < 4; ++oi)
      acc[mi][oi] = (f32x4){0.f, 0.f, 0.f, 0.f};

  const _Float16* gA = A + (size_t)(m0 + trow) * lda + tsegl;
  const _Float16* gB = W + (size_t)(o0 + trow) * ldb + tsegl;

  for (int k0 = 0; k0 < K; k0 += 64) {
#pragma unroll
    for (int i = 0; i < 4; ++i) {
      gload_lds16(gA + (size_t)(32 * i) * lda + k0, lA + ((size_t)i * 256 + tid) * 8);
      gload_lds16(gB + (size_t)(32 * i) * ldb + k0, lB + ((size_t)i * 256 + tid) * 8);
    }
    __syncthreads();
#pragma unroll
    for (int ks = 0; ks < 64; ks += 32) {
      half8 af[4], bf[4];
#pragma unroll
      for (int mi = 0; mi < 4; ++mi)
        af[mi] = *(const half8*)&lA[(wm + mi * 16 + lr) * 64 + ((((ks >> 3) + lq) ^ sw)) * 8];
#pragma unroll
      for (int oi = 0; oi < 4; ++oi)
        bf[oi] = *(const half8*)&lB[(wo + oi * 16 + lr) * 64 + ((((ks >> 3) + lq) ^ sw)) * 8];
#pragma unroll
      for (int mi = 0; mi < 4; ++mi)
#pragma unroll
        for (int oi = 0; oi < 4; ++oi)
          acc[mi][oi] = __builtin_amdgcn_mfma_f32_16x16x32_f16(af[mi], bf[oi], acc[mi][oi], 0, 0, 0);
    }
    __syncthreads();
  }

#pragma unroll
  for (int mi = 0; mi < 4; ++mi)
#pragma unroll
    for (int oi = 0; oi < 4; ++oi)
#pragma unroll
      for (int r = 0; r < 4; ++r)
        lsm[(wm + mi * 16 + lq * 4 + r) * 128 + (wo + oi * 16 + lr)] = (_Float16)acc[mi][oi][r];
  __syncthreads();

  int tcol = (tid & 15) * 8;
  int rbase = tid >> 4;
  float s8[8], q8[8];
#pragma unroll
  for (int j = 0; j < 8; ++j) { s8[j] = 0.f; q8[j] = 0.f; }
#pragma unroll
  for (int i = 0; i < 8; ++i) {
    int row = rbase + i * 16;
    int4 id = sIdx[row];
    float4 w = sWt[row];
    half8 y = *(half8*)&lsm[row * 128 + tcol];
    int zc = zcol0 + o0 + tcol;
    half8 a  = *(const half8*)&Z[(size_t)id.x * ldz + zc];
    half8 b2 = *(const half8*)&Z[(size_t)id.y * ldz + zc];
    half8 c2 = *(const half8*)&Z[(size_t)id.z * ldz + zc];
    half8 o;
#pragma unroll
    for (int j = 0; j < 8; ++j) {
      float v = (float)y[j] + w.x * (float)a[j] + w.y * (float)b2[j] + w.z * (float)c2[j];
      o[j] = (_Float16)v;
      s8[j] += v; q8[j] += v * v;
    }
    *(half8*)&Y[(size_t)(m0 + row) * ldy + o0 + tcol] = o;
  }
#pragma unroll
  for (int j = 0; j < 8; ++j) {
    atomicAdd(&sStat[tcol + j], s8[j]);
    atomicAdd(&sStat[128 + tcol + j], q8[j]);
  }
  __syncthreads();
  if (tid < 128) {
    atomicAdd(&sum[o0 + tid], sStat[tid]);
    atomicAdd(&sumsq[o0 + tid], sStat[128 + tid]);
  }
}

// ---- decoder GEMM: folded BN-finalize + normrelu on A, f32 out/acc into D,
//      optional fused D-stats; swz pairs (m,o=0)/(m,o=1) on one XCD for Y3 L2 reuse ----
__global__ __launch_bounds__(256) void k_gemm_dec_acc(const _Float16* __restrict__ A,
                                                      const float* __restrict__ sumc,
                                                      const float* __restrict__ sumsqc,
                                                      const float* __restrict__ g,
                                                      const float* __restrict__ b,
                                                      float invM, int c0, int Oglob,
                                                      const _Float16* __restrict__ W,
                                                      float* __restrict__ D,
                                                      int K, int lda, int ldb, int ldc,
                                                      int accum, int do_stats, int swz,
                                                      float* __restrict__ dsum,
                                                      float* __restrict__ dsumsq) {
  __shared__ __align__(16) _Float16 lA[128 * 64];
  __shared__ __align__(16) _Float16 lB[128 * 64];
  __shared__ float sScale[2048];
  __shared__ float sShift[2048];
  __shared__ float sStat[256];
  int tid = threadIdx.x;
  int m0, o0;
  if (swz) {
    int bid = blockIdx.y * gridDim.x + blockIdx.x;
    int mlow = bid & 7, oo = (bid >> 3) & 1, mhigh = bid >> 4;
    m0 = (mhigh * 8 + mlow) * 128;
    o0 = oo * 128;
  } else {
    m0 = blockIdx.x * 128; o0 = blockIdx.y * 128;
  }
  for (int c = tid; c < K; c += 256) {
    int gc = c0 + c;
    float sc = 0.f, sh = 0.f;
    if (gc < Oglob) {
      float mean = sumc[c] * invM;
      float var = sumsqc[c] * invM - mean * mean;
      sc = g[gc] * rsqrtf(var + 1e-5f);
      sh = b[gc] - mean * sc;
    }
    sScale[c] = sc; sShift[c] = sh;
  }
  sStat[tid] = 0.f;
  __syncthreads();

  int lane = tid & 63, wv = tid >> 6;
  int wm = (wv & 1) * 64, wo = (wv >> 1) * 64;
  int lr = lane & 15, lq = lane >> 4;
  int trow = tid >> 3;
  int tsegl = (((tid & 7) ^ (trow & 7))) * 8;
  int sw = lr & 7;

  f32x4 acc[4][4];
#pragma unroll
  for (int mi = 0; mi < 4; ++mi)
#pragma unroll
    for (int oi = 0; oi < 4; ++oi)
      acc[mi][oi] = (f32x4){0.f, 0.f, 0.f, 0.f};

  const _Float16* gA = A + (size_t)(m0 + trow) * lda + tsegl;
  const _Float16* gB = W + (size_t)(o0 + trow) * ldb + tsegl;

  for (int k0 = 0; k0 < K; k0 += 64) {
#pragma unroll
    for (int i = 0; i < 4; ++i)
      gload_lds16(gB + (size_t)(32 * i) * ldb + k0, lB + ((size_t)i * 256 + tid) * 8);
    float sc[8], sh[8];
#pragma unroll
    for (int j = 0; j < 8; ++j) { sc[j] = sScale[k0 + tsegl + j]; sh[j] = sShift[k0 + tsegl + j]; }
#pragma unroll
    for (int i = 0; i < 4; ++i) {
      half8 v = *(const half8*)(gA + (size_t)(32 * i) * lda + k0);
      half8 o;
#pragma unroll
      for (int j = 0; j < 8; ++j)
        o[j] = (_Float16)fmaxf((float)v[j] * sc[j] + sh[j], 0.f);
      *(half8*)&lA[((size_t)i * 256 + tid) * 8] = o;
    }
    __syncthreads();
#pragma unroll
    for (int ks = 0; ks < 64; ks += 32) {
      half8 af[4], bf[4];
#pragma unroll
      for (int mi = 0; mi < 4; ++mi)
        af[mi] = *(const half8*)&lA[(wm + mi * 16 + lr) * 64 + ((((ks >> 3) + lq) ^ sw)) * 8];
#pragma unroll
      for (int oi = 0; oi < 4; ++oi)
        bf[oi] = *(const half8*)&lB[(wo + oi * 16 + lr) * 64 + ((((ks >> 3) + lq) ^ sw)) * 8];
#pragma unroll
      for (int mi = 0; mi < 4; ++mi)
#pragma unroll
        for (int oi = 0; oi < 4; ++oi)
          acc[mi][oi] = __builtin_amdgcn_mfma_f32_16x16x32_f16(af[mi], bf[oi], acc[mi][oi], 0, 0, 0);
    }
    __syncthreads();
  }

  float ps[4], pq[4];
#pragma unroll
  for (int oi = 0; oi < 4; ++oi) { ps[oi] = 0.f; pq[oi] = 0.f; }
#pragma unroll
  for (int mi = 0; mi < 4; ++mi)
#pragma unroll
    for (int oi = 0; oi < 4; ++oi) {
      int col = o0 + wo + oi * 16 + lr;
      int rowb = m0 + wm + mi * 16 + lq * 4;
#pragma unroll
      for (int r = 0; r < 4; ++r) {
        size_t idx = (size_t)(rowb + r) * ldc + col;
        float v = acc[mi][oi][r];
        if (accum) v += D[idx];
        D[idx] = v;
        if (do_stats) { ps[oi] += v; pq[oi] += v * v; }
      }
    }
  if (do_stats) {
#pragma unroll
    for (int oi = 0; oi < 4; ++oi) {
      int tc = wo + oi * 16 + lr;
      atomicAdd(&sStat[tc], ps[oi]);
      atomicAdd(&sStat[128 + tc], pq[oi]);
    }
    __syncthreads();
    if (tid < 128) {
      atomicAdd(&dsum[o0 + tid], sStat[tid]);
      atomicAdd(&dsumsq[o0 + tid], sStat[128 + tid]);
    }
  }
}

// ---------------- final dot; BN finalize hoisted into LDS once per block ----------------
__global__ __launch_bounds__(256) void k_final_dot2(const float* __restrict__ H,
                                                    const float* __restrict__ w,
                                                    const float* __restrict__ dsum,
                                                    const float* __restrict__ dsumsq,
                                                    const float* __restrict__ g,
                                                    const float* __restrict__ b,
                                                    float invM,
                                                    float* __restrict__ out, int Mtot) {
  __shared__ float sSc[256], sSh[256];
  int tid = threadIdx.x;
  {
    int c = tid;
    float mean = dsum[c] * invM;
    float var = dsumsq[c] * invM - mean * mean;
    float sc = g[c] * rsqrtf(var + 1e-5f);
    sSc[c] = sc;
    sSh[c] = b[c] - mean * sc;
  }
  __syncthreads();
  int lane = tid & 63, wv = tid >> 6;
  int r = blockIdx.x * 4 + wv;
  if (r >= Mtot) return;
  const float* h = H + (size_t)r * 256;
  float s = 0.f;
  for (int c = lane; c < 256; c += 64)
    s += fmaxf(h[c] * sSc[c] + sSh[c], 0.f) * w[c];
#pragma unroll
  for (int o = 32; o > 0; o >>= 1) s += __shfl_down(s, o, 64);
  if (lane == 0) out[r] = s;
}

extern "C" void kernel_launch(void* const* d_in, const int* in_sizes, int n_in,
                              void* d_out, int out_size, void* d_ws, size_t ws_size,
                              hipStream_t stream) {
  (void)in_sizes; (void)n_in; (void)out_size;
  const int B = 16;
  const float* xyzs[5]; const float* xs[5];
  for (int i = 0; i < 5; ++i) { xyzs[i] = (const float*)d_in[2 * i]; xs[i] = (const float*)d_in[2 * i + 1]; }
  const float* wlin[4] = {(const float*)d_in[10], (const float*)d_in[13], (const float*)d_in[16], (const float*)d_in[19]};
  const float* glin[4] = {(const float*)d_in[11], (const float*)d_in[14], (const float*)d_in[17], (const float*)d_in[20]};
  const float* blin[4] = {(const float*)d_in[12], (const float*)d_in[15], (const float*)d_in[18], (const float*)d_in[21]};
  const float* wdec0 = (const float*)d_in[22];
  const float* gdec  = (const float*)d_in[23];
  const float* bdec  = (const float*)d_in[24];
  const float* wdec1 = (const float*)d_in[25];
  float* outp = (float*)d_out;

  const int ch[5] = {64, 128, 256, 512, 1024};
  const int np[5] = {2048, 512, 128, 32, 8};

  char* base = (char*)d_ws;
  size_t off = 0;
  auto alloc = [&](size_t bytes) -> char* {
    char* p = base + off;
    off += (bytes + 255) & ~(size_t)255;
    return p;
  };

  _Float16* Wbuf = (_Float16*)alloc((size_t)2048 * 1984 * 2);
  _Float16* Wdec = (_Float16*)alloc((size_t)256 * 2048 * 2);
  _Float16* tT[5];
  for (int i = 0; i < 5; ++i) tT[i] = (_Float16*)alloc((size_t)B * np[i] * ch[i] * 2);
  int4* idxAll = (int4*)alloc(43520 * sizeof(int4));
  float4* wbAll = (float4*)alloc(43520 * sizeof(float4));
  float* statsPool = (float*)alloc(8 * 2 * 2048 * sizeof(float));
  float* scaleA = (float*)alloc(2048 * sizeof(float));
  float* shiftA = (float*)alloc(2048 * sizeof(float));
  _Float16* Zreg = (_Float16*)alloc((size_t)8192 * 2048 * 2);
  float* D = (float*)alloc((size_t)32768 * 256 * 4);
  size_t ybytes_chunk = 40370176;
  size_t ybytes_full = (size_t)32768 * 2048 * 2;
  int use_full = (ws_size >= off + ybytes_full + 256);
  char* Yreg = alloc(use_full ? ybytes_full : ybytes_chunk);
  _Float16* Y0 = (_Float16*)Yreg;
  _Float16* Y1 = (_Float16*)(Yreg + (size_t)512 * 1536 * 2);
  _Float16* Y2 = (_Float16*)(Yreg + (size_t)(512 * 1536 + 2048 * 1792) * 2);
  _Float16* Ychunk = (_Float16*)Yreg;
  _Float16* Y3full = (_Float16*)Yreg;
  if (off > ws_size) return;

  hipMemsetAsync(statsPool, 0, 8 * 2 * 2048 * sizeof(float), stream);

  // merged transpose
  {
    TPack p;
    int cum = 0;
    for (int i = 0; i < 5; ++i) {
      p.in[i] = xs[i]; p.out[i] = tT[i]; p.C[i] = ch[i]; p.N[i] = np[i];
      p.cum[i] = cum;
      cum += (ch[i] / 32) * ((np[i] + 31) / 32) * B;
    }
    p.cum[5] = cum;
    k_transpose_all<<<cum, dim3(32, 8), 0, stream>>>(p);
  }
  {
    size_t tot4 = (size_t)256 * 2048 / 4;
    k_cast_pad_w<<<dim3((unsigned)((tot4 + 255) / 256)), 256, 0, stream>>>(wdec0, Wdec, 256, 1984, 256, 2048);
  }

  const int N1s[4] = {32, 128, 512, 2048};
  const int Ss[4]  = {8, 32, 128, 512};
  const int C1s[4] = {512, 256, 128, 64};
  const int C2s[4] = {1024, 1536, 1792, 1920};
  const int Os[4]  = {1536, 1792, 1920, 1984};
  const int obase[4] = {0, 512, 2560, 10752};
  _Float16* Ys[3] = {Y0, Y1, Y2};

  // merged kNN (4 threads per query)
  {
    KPack kp;
    int cum = 0;
    for (int st = 0; st < 4; ++st) {
      kp.q[st] = xyzs[3 - st]; kp.p[st] = xyzs[4 - st];
      kp.N1[st] = N1s[st]; kp.S[st] = Ss[st];
      kp.cum[st] = cum;
      cum += ((N1s[st] * 4 + 255) / 256) * B;
      kp.obase[st] = obase[st];
    }
    kp.cum[4] = cum;
    k_knn_all<<<cum, 256, 0, stream>>>(kp, idxAll, wbAll);
  }

  // ---- stages 0..2 (R12 structure: fused-anorm Z GEMM + separate finalize) ----
  for (int st = 0; st < 3; ++st) {
    int N1 = N1s[st], C1 = C1s[st], C2 = C2s[st], O = Os[st];
    int Ktot = C1 + C2;
    int M = B * N1, Msrc = B * Ss[st];
    const _Float16* H = (st == 0) ? tT[4] : Ys[st - 1];
    _Float16* Y = Ys[st];
    float* sum = statsPool + st * 2 * 2048;
    float* sumsq = sum + 2048;

    size_t wt = (size_t)O * Ktot / 4;
    k_cast_pad_w<<<(unsigned)((wt + 255) / 256), 256, 0, stream>>>(wlin[st], Wbuf, O, Ktot, O, Ktot);

    k_gemm_anorm<<<dim3(Msrc / 128, O / 128), 256, 0, stream>>>(H, scaleA, shiftA, st != 0,
                                                                Wbuf + C1, Zreg, C2, C2, Ktot, O);
    k_gemm_yis<<<dim3(M / 128, O / 128), 256, 0, stream>>>(tT[3 - st], Wbuf, Zreg,
                                                           idxAll + obase[st], wbAll + obase[st],
                                                           Y, sum, sumsq,
                                                           C1, C1, Ktot, O, O, 0, 0);
    k_bn_finalize<<<(O + 255) / 256, 256, 0, stream>>>(sum, sumsq, glin[st], blin[st], scaleA, shiftA, O, O, 1.f / M);
  }

  // ---- stage 3 (R12 structure + measured swizzles) ----
  {
    int C1 = 64, C2 = 1920, O = 1984, M = 32768, Msrc = 8192;
    int Ktot = 1984;
    size_t wt = (size_t)2048 * Ktot / 4;
    k_cast_pad_w<<<(unsigned)((wt + 255) / 256), 256, 0, stream>>>(wlin[3], Wbuf, O, Ktot, 2048, Ktot);

    // Z3 (8192 x 2048) = normrelu(Y2) . Wint^T (fused anorm)
    k_gemm_anorm<<<dim3(Msrc / 128, 16), 256, 0, stream>>>(Y2, scaleA, shiftA, 1,
                                                           Wbuf + C1, Zreg, C2, C2, Ktot, 2048);

    float* dsum = statsPool + 7 * 2 * 2048;
    float* dsumsq = dsum + 2048;
    if (use_full) {
      float* sum = statsPool + 3 * 2 * 2048;
      float* sumsq = sum + 2048;
      // Y3 (32768 x 2048), 128x128 tiles, XCD-swizzled (R10-verified best yis)
      k_gemm_yis<<<dim3(256, 16), 256, 0, stream>>>(tT[0], Wbuf, Zreg,
                                                    idxAll + obase[3], wbAll + obase[3],
                                                    Y3full, sum, sumsq,
                                                    C1, C1, Ktot, 2048, 2048, 0, 1);
      // D = normrelu(Y3).Wdec^T, K=2048, pair-swizzled for Y3 L2 reuse, fused D-stats
      k_gemm_dec_acc<<<dim3(256, 2), 256, 0, stream>>>(Y3full, sum, sumsq,
                                                       glin[3], blin[3], 1.f / M, 0, O,
                                                       Wdec, D, 2048, 2048, 2048, 256,
                                                       0, 1, 1, dsum, dsumsq);
    } else {
      for (int c0 = 0; c0 < 2048; c0 += 512) {
        float* sum = statsPool + (3 + c0 / 512) * 2 * 2048;
        float* sumsq = sum + 2048;
        k_gemm_yis<<<dim3(M / 128, 4), 256, 0, stream>>>(tT[0], Wbuf + (size_t)c0 * Ktot, Zreg,
                                                         idxAll + obase[3], wbAll + obase[3],
                                                         Ychunk, sum, sumsq,
                                                         C1, C1, Ktot, 512, 2048, c0, 0);
        k_gemm_dec_acc<<<dim3(M / 128, 2), 256, 0, stream>>>(Ychunk, sum, sumsq,
                                                             glin[3], blin[3], 1.f / M, c0, O,
                                                             Wdec + c0, D, 512, 512, 2048, 256,
                                                             c0 != 0, c0 == 1536, 0, dsum, dsumsq);
      }
    }
  }

  // ---- final dot (decoder BN finalize hoisted in-block) ----
  {
    int M = 32768;
    float* dsum = statsPool + 7 * 2 * 2048;
    float* dsumsq = dsum + 2048;
    k_final_dot2<<<M / 4, 256, 0, stream>>>(D, wdec1, dsum, dsumsq, gdec, bdec, 1.f / M, outp, M);
  }
}